// Round 7
// baseline (896.075 us; speedup 1.0000x reference)
//
#include <hip/hip_runtime.h>
#include <hip/hip_bf16.h>

#define DFEAT 256

typedef __bf16 bf16x8 __attribute__((ext_vector_type(8)));
typedef __bf16 bf16x4 __attribute__((ext_vector_type(4)));
typedef float  f32x4  __attribute__((ext_vector_type(4)));

// ---------------------------------------------------------------------------
// CSR build: histogram -> hierarchical scan -> cursor scatter (sorted records)
// ---------------------------------------------------------------------------
__global__ void hist_kernel(const int* __restrict__ dst, int nE, int* __restrict__ P) {
    for (int e = blockIdx.x * blockDim.x + threadIdx.x; e < nE; e += gridDim.x * blockDim.x)
        atomicAdd(&P[dst[e] + 1], 1);
}

__global__ __launch_bounds__(256) void scan_block(int* __restrict__ a, int n, int* __restrict__ bsum) {
    __shared__ int wsum[4];
    const int tid = threadIdx.x;
    const int lane = tid & 63, wv = tid >> 6;
    const int idx = blockIdx.x * 2048 + tid * 8;
    int v[8];
    #pragma unroll
    for (int i = 0; i < 8; ++i) v[i] = (idx + i < n) ? a[idx + i] : 0;
    #pragma unroll
    for (int i = 1; i < 8; ++i) v[i] += v[i - 1];
    int tsum = v[7];
    int sc = tsum;
    #pragma unroll
    for (int off = 1; off < 64; off <<= 1) {
        int t = __shfl_up(sc, off);
        if (lane >= off) sc += t;
    }
    if (lane == 63) wsum[wv] = sc;
    __syncthreads();
    int wadd = 0;
    for (int w2 = 0; w2 < wv; ++w2) wadd += wsum[w2];
    int texcl = sc - tsum + wadd;
    #pragma unroll
    for (int i = 0; i < 8; ++i)
        if (idx + i < n) a[idx + i] = v[i] + texcl;
    if (tid == 255) bsum[blockIdx.x] = sc + wadd;
}

__global__ void scan_sums(int* __restrict__ bsum, int nb) {
    int lane = threadIdx.x;
    int v = (lane < nb) ? bsum[lane] : 0;
    #pragma unroll
    for (int off = 1; off < 64; off <<= 1) {
        int t = __shfl_up(v, off);
        if (lane >= off) v += t;
    }
    if (lane < nb) bsum[lane] = v;
}

__global__ __launch_bounds__(256) void scan_add(int* __restrict__ a, int n, const int* __restrict__ bsum) {
    if (blockIdx.x == 0) return;
    int add = bsum[blockIdx.x - 1];
    int idx = blockIdx.x * 2048 + threadIdx.x * 8;
    #pragma unroll
    for (int i = 0; i < 8; ++i)
        if (idx + i < n) a[idx + i] += add;
}

__global__ void copy_int(const int* __restrict__ src, int* __restrict__ dst, int n) {
    for (int i = blockIdx.x * blockDim.x + threadIdx.x; i < n; i += gridDim.x * blockDim.x)
        dst[i] = src[i];
}

__global__ void fill_kernel(const int* __restrict__ dst, const int* __restrict__ src,
                            const float* __restrict__ w, int nE,
                            int* __restrict__ cursor,
                            int* __restrict__ rsrc, float* __restrict__ rw) {
    for (int e = blockIdx.x * blockDim.x + threadIdx.x; e < nE; e += gridDim.x * blockDim.x) {
        int pos = atomicAdd(&cursor[dst[e]], 1);
        rsrc[pos] = src[e];
        rw[pos]   = w[e];
    }
}

// ---------------------------------------------------------------------------
__global__ __launch_bounds__(256) void f32_to_bf16_kernel(
    const float* __restrict__ in, __bf16* __restrict__ out, int n8)
{
    for (int i = blockIdx.x * blockDim.x + threadIdx.x; i < n8; i += gridDim.x * blockDim.x) {
        float4 a = *reinterpret_cast<const float4*>(in + (size_t)i * 8);
        float4 b = *reinterpret_cast<const float4*>(in + (size_t)i * 8 + 4);
        bf16x8 v;
        v[0] = (__bf16)a.x; v[1] = (__bf16)a.y; v[2] = (__bf16)a.z; v[3] = (__bf16)a.w;
        v[4] = (__bf16)b.x; v[5] = (__bf16)b.y; v[6] = (__bf16)b.z; v[7] = (__bf16)b.w;
        *reinterpret_cast<bf16x8*>(out + (size_t)i * 8) = v;
    }
}

// WcatT[n][k] bf16 [256][512]: k<256 -> Wl[k][n], k>=256 -> Wr[k-256][n]
__global__ __launch_bounds__(256) void wtrans_kernel(
    const float* __restrict__ Wl, const float* __restrict__ Wr, __bf16* __restrict__ out)
{
    int t = blockIdx.x * blockDim.x + threadIdx.x;
    if (t >= 256 * 512) return;
    int n = t >> 9;
    int k = t & 511;
    float v = (k < 256) ? Wl[(size_t)k * 256 + n] : Wr[(size_t)(k - 256) * 256 + n];
    out[t] = (__bf16)v;
}

// ---------------------------------------------------------------------------
// Aggregation: one wave per dst row; 2 edges per wave-step (32 lanes x 16B),
// 16 edges in flight; cross-half combine via shfl_xor(32).   (unchanged)
// ---------------------------------------------------------------------------
__global__ __launch_bounds__(256) void aggregate_bf16(
    const __bf16* __restrict__ xsrc, const int* __restrict__ rsrc,
    const float* __restrict__ rw, const int* __restrict__ rowptr,
    __bf16* __restrict__ mean, int ndst)
{
    int wid  = (blockIdx.x * blockDim.x + threadIdx.x) >> 6;
    int lane = threadIdx.x & 63;
    if (wid >= ndst) return;
    int beg = rowptr[wid], end = rowptr[wid + 1];
    const int half = lane >> 5, hl = lane & 31;
    const __bf16* xcol = xsrc + hl * 8;
    float acc[8];
    #pragma unroll
    for (int i = 0; i < 8; ++i) acc[i] = 0.f;

    int j0 = beg;
    while (j0 < end) {
        int m = end - j0; if (m > 64) m = 64;
        int   sl = (lane < m) ? rsrc[j0 + lane] : 0;
        float wl = (lane < m) ? rw[j0 + lane]   : 0.f;
        int t = 0;
        for (; t + 16 <= m; t += 16) {
            bf16x8 v[8]; float wt[8];
            #pragma unroll
            for (int u = 0; u < 8; ++u) {
                int tt = t + u * 2;
                int e0 = __builtin_amdgcn_readlane(sl, tt);
                int e1 = __builtin_amdgcn_readlane(sl, tt + 1);
                int w0 = __builtin_amdgcn_readlane(__float_as_int(wl), tt);
                int w1 = __builtin_amdgcn_readlane(__float_as_int(wl), tt + 1);
                int s = half ? e1 : e0;
                wt[u] = __int_as_float(half ? w1 : w0);
                v[u] = *reinterpret_cast<const bf16x8*>(xcol + (size_t)s * DFEAT);
            }
            #pragma unroll
            for (int u = 0; u < 8; ++u)
                #pragma unroll
                for (int i = 0; i < 8; ++i) acc[i] += wt[u] * (float)v[u][i];
        }
        for (; t < m; t += 2) {
            int e0 = __builtin_amdgcn_readlane(sl, t);
            int e1 = __builtin_amdgcn_readlane(sl, (t + 1 < 64) ? t + 1 : 63);
            int w0 = __builtin_amdgcn_readlane(__float_as_int(wl), t);
            int w1 = __builtin_amdgcn_readlane(__float_as_int(wl), (t + 1 < 64) ? t + 1 : 63);
            int s = half ? e1 : e0;
            float wv2 = __int_as_float(half ? w1 : w0);
            if (half && t + 1 >= m) wv2 = 0.f;
            bf16x8 v = *reinterpret_cast<const bf16x8*>(xcol + (size_t)s * DFEAT);
            #pragma unroll
            for (int i = 0; i < 8; ++i) acc[i] += wv2 * (float)v[i];
        }
        j0 += m;
    }

    #pragma unroll
    for (int i = 0; i < 8; ++i) acc[i] += __shfl_xor(acc[i], 32);
    float inv = (end > beg) ? 1.0f / (float)(end - beg) : 0.0f;
    if (half == 0) {
        bf16x8 o;
        #pragma unroll
        for (int i = 0; i < 8; ++i) o[i] = (__bf16)(acc[i] * inv);
        *reinterpret_cast<bf16x8*>(mean + (size_t)wid * DFEAT + hl * 8) = o;
    }
}

// ---------------------------------------------------------------------------
// Barrier-free MFMA GEMM: out[i,:] = epi( A[i,:]@Wl + B[i,:]@Wr + bias )
// NO LDS, NO __syncthreads. 256 thr = 4 independent waves; wave w owns
// rows [brow, brow+64) x cols [w*64, w*64+64). K=512 over 8 chunks of 64;
// chunks 0-3 read Amat, 4-7 read Bmat. A fragments straight from global
// (L1 absorbs 4x intra-block reuse; A is streamed once grid-wide);
// B fragments from WT (256KB, L2-resident). Fully unrolled -> 16-deep
// independent load ILP per chunk, compiler-scheduled counted waitcnts,
// 4 waves/SIMD TLP (launch_bounds caps VGPR at 128).
// ---------------------------------------------------------------------------
template<int EPI>
__global__ __launch_bounds__(256, 4) void gemm_mfma(
    const __bf16* __restrict__ Amat, const __bf16* __restrict__ Bmat,
    const __bf16* __restrict__ WT, const float* __restrict__ bias,
    const __bf16* __restrict__ resid, void* __restrict__ outv, int n)
{
    const int tid  = threadIdx.x;
    const int lane = tid & 63;
    const int wv   = tid >> 6;            // wave = col group
    const int lo   = lane & 15;
    const int hi   = lane >> 4;
    const int brow = blockIdx.x * 64;
    const int wcol = wv * 64;
    const int nm1  = n - 1;

    // per-lane byte offsets
    size_t arow[4];
    #pragma unroll
    for (int mm = 0; mm < 4; ++mm) {
        int r = brow + mm * 16 + lo; if (r > nm1) r = nm1;
        arow[mm] = (size_t)r * 512;                 // 256 bf16 = 512 B per row
    }
    size_t wrow[4];
    #pragma unroll
    for (int nn = 0; nn < 4; ++nn)
        wrow[nn] = (size_t)(wcol + nn * 16 + lo) * 1024;  // 512 bf16 = 1024 B per WT row

    const char* Ab = reinterpret_cast<const char*>(Amat);
    const char* Bb = reinterpret_cast<const char*>(Bmat);
    const char* Wb = reinterpret_cast<const char*>(WT);
    const int hib = hi * 16;

    f32x4 acc[4][4];
    #pragma unroll
    for (int i = 0; i < 4; ++i)
        #pragma unroll
        for (int j = 0; j < 4; ++j) acc[i][j] = (f32x4){0.f, 0.f, 0.f, 0.f};

    #pragma unroll
    for (int c = 0; c < 8; ++c) {
        const char* mb = (c < 4) ? Ab : Bb;
        const int koff = (c & 3) * 128;             // byte offset of chunk in 512B row
        const int wkoff = c * 128;                  // byte offset of chunk in 1024B WT row
        bf16x8 av[2][4], bv[2][4];
        #pragma unroll
        for (int ks = 0; ks < 2; ++ks) {
            #pragma unroll
            for (int q = 0; q < 4; ++q) {
                av[ks][q] = *reinterpret_cast<const bf16x8*>(mb + arow[q] + koff + ks * 64 + hib);
                bv[ks][q] = *reinterpret_cast<const bf16x8*>(Wb + wrow[q] + wkoff + ks * 64 + hib);
            }
        }
        #pragma unroll
        for (int ks = 0; ks < 2; ++ks)
            #pragma unroll
            for (int mm = 0; mm < 4; ++mm)
                #pragma unroll
                for (int nn = 0; nn < 4; ++nn)
                    acc[mm][nn] = __builtin_amdgcn_mfma_f32_16x16x32_bf16(
                        av[ks][mm], bv[ks][nn], acc[mm][nn], 0, 0, 0);
    }

    // epilogue: D col = lane&15, row = (lane>>4)*4 + reg
    #pragma unroll
    for (int mm = 0; mm < 4; ++mm) {
        #pragma unroll
        for (int nn = 0; nn < 4; ++nn) {
            int col = wcol + nn * 16 + lo;
            float bv2 = bias[col];
            #pragma unroll
            for (int r = 0; r < 4; ++r) {
                int grow = brow + mm * 16 + hi * 4 + r;
                if (grow >= n) continue;
                float v = acc[mm][nn][r] + bv2;
                if (EPI == 1) {
                    float rv = (float)resid[(size_t)grow * DFEAT + col];
                    ((__bf16*)outv)[(size_t)grow * DFEAT + col] =
                        (__bf16)(rv + fmaxf(v, 0.f));
                } else {
                    ((float*)outv)[(size_t)grow * DFEAT + col] = v;
                }
            }
        }
    }
}

// ---------------------------------------------------------------------------
extern "C" void kernel_launch(void* const* d_in, const int* in_sizes, int n_in,
                              void* d_out, int out_size, void* d_ws, size_t ws_size,
                              hipStream_t stream) {
    const float* x_user  = (const float*)d_in[0];
    const float* x_movie = (const float*)d_in[1];
    const int*   src_um  = (const int*)d_in[2];
    const int*   dst_um  = (const int*)d_in[3];
    const float* w_um    = (const float*)d_in[4];
    const int*   src_mu  = (const int*)d_in[5];
    const int*   dst_mu  = (const int*)d_in[6];
    const float* w_mu    = (const float*)d_in[7];
    const float* c1_um_Wl = (const float*)d_in[8];
    const float* c1_um_Wr = (const float*)d_in[9];
    const float* c1_um_b  = (const float*)d_in[10];
    const float* c1_mu_Wl = (const float*)d_in[11];
    const float* c1_mu_Wr = (const float*)d_in[12];
    const float* c1_mu_b  = (const float*)d_in[13];
    const float* c2_um_Wl = (const float*)d_in[14];
    const float* c2_um_Wr = (const float*)d_in[15];
    const float* c2_um_b  = (const float*)d_in[16];
    const float* c2_mu_Wl = (const float*)d_in[17];
    const float* c2_mu_Wr = (const float*)d_in[18];
    const float* c2_mu_b  = (const float*)d_in[19];

    const int NU = in_sizes[0] / DFEAT;
    const int NM = in_sizes[1] / DFEAT;
    const int E_um = in_sizes[2];
    const int E_mu = in_sizes[5];

    char* p = (char*)d_ws;
    auto carve = [&](size_t bytes) { char* r = p; p += (bytes + 255) & ~(size_t)255; return r; };
    int* rowptr_m = (int*)carve((size_t)(NM + 1) * 4);
    int* rowptr_u = (int*)carve((size_t)(NU + 1) * 4);
    int* cursor_m = (int*)carve((size_t)NM * 4);
    int* cursor_u = (int*)carve((size_t)NU * 4);
    int* bsum_m   = (int*)carve(64 * 4);
    int* bsum_u   = (int*)carve(64 * 4);
    __bf16* xu_bf = (__bf16*)carve((size_t)NU * DFEAT * 2);
    __bf16* xm_bf = (__bf16*)carve((size_t)NM * DFEAT * 2);
    __bf16* ru_bf = (__bf16*)carve((size_t)NU * DFEAT * 2);
    __bf16* rm_bf = (__bf16*)carve((size_t)NM * DFEAT * 2);
    __bf16* wt_c1um = (__bf16*)carve(256 * 512 * 2);
    __bf16* wt_c1mu = (__bf16*)carve(256 * 512 * 2);
    __bf16* wt_c2um = (__bf16*)carve(256 * 512 * 2);
    __bf16* wt_c2mu = (__bf16*)carve(256 * 512 * 2);

    char* dtail = (char*)d_out + (size_t)(NU + NM) * DFEAT * 2;
    int*   rsrc_m = (int*)  (dtail);
    float* rw_m   = (float*)(dtail + (size_t)E_um * 4);
    int*   rsrc_u = (int*)  (dtail + (size_t)E_um * 8);
    float* rw_u   = (float*)(dtail + (size_t)E_um * 8 + (size_t)E_mu * 4);

    __bf16* mean1_u = (__bf16*)d_out;
    __bf16* mean1_m = (__bf16*)d_out + (size_t)NU * DFEAT;
    float* out_user  = (float*)d_out;
    float* out_movie = (float*)d_out + (size_t)NU * DFEAT;

    // ---- CSR build ----
    hipMemsetAsync(rowptr_m, 0, (size_t)(NM + 1) * 4, stream);
    hipMemsetAsync(rowptr_u, 0, (size_t)(NU + 1) * 4, stream);
    hist_kernel<<<2048, 256, 0, stream>>>(dst_um, E_um, rowptr_m);
    hist_kernel<<<2048, 256, 0, stream>>>(dst_mu, E_mu, rowptr_u);
    const int nbM = (NM + 1 + 2047) / 2048;
    const int nbU = (NU + 1 + 2047) / 2048;
    scan_block<<<nbM, 256, 0, stream>>>(rowptr_m, NM + 1, bsum_m);
    scan_block<<<nbU, 256, 0, stream>>>(rowptr_u, NU + 1, bsum_u);
    scan_sums<<<1, 64, 0, stream>>>(bsum_m, nbM);
    scan_sums<<<1, 64, 0, stream>>>(bsum_u, nbU);
    scan_add<<<nbM, 256, 0, stream>>>(rowptr_m, NM + 1, bsum_m);
    scan_add<<<nbU, 256, 0, stream>>>(rowptr_u, NU + 1, bsum_u);
    copy_int<<<256, 256, 0, stream>>>(rowptr_m, cursor_m, NM);
    copy_int<<<256, 256, 0, stream>>>(rowptr_u, cursor_u, NU);
    fill_kernel<<<2048, 256, 0, stream>>>(dst_um, src_um, w_um, E_um, cursor_m, rsrc_m, rw_m);
    fill_kernel<<<2048, 256, 0, stream>>>(dst_mu, src_mu, w_mu, E_mu, cursor_u, rsrc_u, rw_u);

    // ---- bf16 features + transposed weights ----
    f32_to_bf16_kernel<<<2048, 256, 0, stream>>>(x_user, xu_bf, NU * DFEAT / 8);
    f32_to_bf16_kernel<<<2048, 256, 0, stream>>>(x_movie, xm_bf, NM * DFEAT / 8);
    wtrans_kernel<<<512, 256, 0, stream>>>(c1_um_Wl, c1_um_Wr, wt_c1um);
    wtrans_kernel<<<512, 256, 0, stream>>>(c1_mu_Wl, c1_mu_Wr, wt_c1mu);
    wtrans_kernel<<<512, 256, 0, stream>>>(c2_um_Wl, c2_um_Wr, wt_c2um);
    wtrans_kernel<<<512, 256, 0, stream>>>(c2_mu_Wl, c2_mu_Wr, wt_c2mu);

    // ---- layer 1 ----
    aggregate_bf16<<<(NM + 3) / 4, 256, 0, stream>>>(xu_bf, rsrc_m, rw_m, rowptr_m, mean1_m, NM);
    aggregate_bf16<<<(NU + 3) / 4, 256, 0, stream>>>(xm_bf, rsrc_u, rw_u, rowptr_u, mean1_u, NU);
    gemm_mfma<1><<<(NM + 63) / 64, 256, 0, stream>>>(mean1_m, xm_bf, wt_c1um, c1_um_b, xm_bf, rm_bf, NM);
    gemm_mfma<1><<<(NU + 63) / 64, 256, 0, stream>>>(mean1_u, xu_bf, wt_c1mu, c1_mu_b, xu_bf, ru_bf, NU);

    // ---- layer 2 ----
    __bf16* mean2_m = xm_bf;
    __bf16* mean2_u = xu_bf;
    aggregate_bf16<<<(NM + 3) / 4, 256, 0, stream>>>(ru_bf, rsrc_m, rw_m, rowptr_m, mean2_m, NM);
    aggregate_bf16<<<(NU + 3) / 4, 256, 0, stream>>>(rm_bf, rsrc_u, rw_u, rowptr_u, mean2_u, NU);
    gemm_mfma<0><<<(NM + 63) / 64, 256, 0, stream>>>(mean2_m, rm_bf, wt_c2um, c2_um_b, nullptr, out_movie, NM);
    gemm_mfma<0><<<(NU + 63) / 64, 256, 0, stream>>>(mean2_u, ru_bf, wt_c2mu, c2_mu_b, nullptr, out_user, NU);
}

// Round 8
// 745.153 us; speedup vs baseline: 1.2025x; 1.2025x over previous
//
#include <hip/hip_runtime.h>
#include <hip/hip_bf16.h>

#define DFEAT 256

typedef __bf16 bf16x8 __attribute__((ext_vector_type(8)));
typedef __bf16 bf16x4 __attribute__((ext_vector_type(4)));
typedef float  f32x4  __attribute__((ext_vector_type(4)));

// ---------------------------------------------------------------------------
// CSR build: histogram -> hierarchical scan -> cursor scatter (sorted records)
// ---------------------------------------------------------------------------
__global__ void hist_kernel(const int* __restrict__ dst, int nE, int* __restrict__ P) {
    for (int e = blockIdx.x * blockDim.x + threadIdx.x; e < nE; e += gridDim.x * blockDim.x)
        atomicAdd(&P[dst[e] + 1], 1);
}

__global__ __launch_bounds__(256) void scan_block(int* __restrict__ a, int n, int* __restrict__ bsum) {
    __shared__ int wsum[4];
    const int tid = threadIdx.x;
    const int lane = tid & 63, wv = tid >> 6;
    const int idx = blockIdx.x * 2048 + tid * 8;
    int v[8];
    #pragma unroll
    for (int i = 0; i < 8; ++i) v[i] = (idx + i < n) ? a[idx + i] : 0;
    #pragma unroll
    for (int i = 1; i < 8; ++i) v[i] += v[i - 1];
    int tsum = v[7];
    int sc = tsum;
    #pragma unroll
    for (int off = 1; off < 64; off <<= 1) {
        int t = __shfl_up(sc, off);
        if (lane >= off) sc += t;
    }
    if (lane == 63) wsum[wv] = sc;
    __syncthreads();
    int wadd = 0;
    for (int w2 = 0; w2 < wv; ++w2) wadd += wsum[w2];
    int texcl = sc - tsum + wadd;
    #pragma unroll
    for (int i = 0; i < 8; ++i)
        if (idx + i < n) a[idx + i] = v[i] + texcl;
    if (tid == 255) bsum[blockIdx.x] = sc + wadd;
}

__global__ void scan_sums(int* __restrict__ bsum, int nb) {
    int lane = threadIdx.x;
    int v = (lane < nb) ? bsum[lane] : 0;
    #pragma unroll
    for (int off = 1; off < 64; off <<= 1) {
        int t = __shfl_up(v, off);
        if (lane >= off) v += t;
    }
    if (lane < nb) bsum[lane] = v;
}

__global__ __launch_bounds__(256) void scan_add(int* __restrict__ a, int n, const int* __restrict__ bsum) {
    if (blockIdx.x == 0) return;
    int add = bsum[blockIdx.x - 1];
    int idx = blockIdx.x * 2048 + threadIdx.x * 8;
    #pragma unroll
    for (int i = 0; i < 8; ++i)
        if (idx + i < n) a[idx + i] += add;
}

__global__ void copy_int(const int* __restrict__ src, int* __restrict__ dst, int n) {
    for (int i = blockIdx.x * blockDim.x + threadIdx.x; i < n; i += gridDim.x * blockDim.x)
        dst[i] = src[i];
}

__global__ void fill_kernel(const int* __restrict__ dst, const int* __restrict__ src,
                            const float* __restrict__ w, int nE,
                            int* __restrict__ cursor,
                            int* __restrict__ rsrc, float* __restrict__ rw) {
    for (int e = blockIdx.x * blockDim.x + threadIdx.x; e < nE; e += gridDim.x * blockDim.x) {
        int pos = atomicAdd(&cursor[dst[e]], 1);
        rsrc[pos] = src[e];
        rw[pos]   = w[e];
    }
}

// ---------------------------------------------------------------------------
__global__ __launch_bounds__(256) void f32_to_bf16_kernel(
    const float* __restrict__ in, __bf16* __restrict__ out, int n8)
{
    for (int i = blockIdx.x * blockDim.x + threadIdx.x; i < n8; i += gridDim.x * blockDim.x) {
        float4 a = *reinterpret_cast<const float4*>(in + (size_t)i * 8);
        float4 b = *reinterpret_cast<const float4*>(in + (size_t)i * 8 + 4);
        bf16x8 v;
        v[0] = (__bf16)a.x; v[1] = (__bf16)a.y; v[2] = (__bf16)a.z; v[3] = (__bf16)a.w;
        v[4] = (__bf16)b.x; v[5] = (__bf16)b.y; v[6] = (__bf16)b.z; v[7] = (__bf16)b.w;
        *reinterpret_cast<bf16x8*>(out + (size_t)i * 8) = v;
    }
}

// Packed fragment-major weights: frag f = ncg*16 + kc  (ncg = col-group 0..15,
// kc = k-chunk 0..15 of 32 k each); within frag, lane l = hi*16+lo holds 8 bf16
// at byte f*1024 + l*16:  value[j] = Wcat[k = kc*32 + hi*8 + j][col = ncg*16+lo]
// where Wcat rows 0..255 = Wl, 256..511 = Wr.  B-frag loads become 1KB
// fully-coalesced reads.
__global__ __launch_bounds__(256) void wtrans_kernel(
    const float* __restrict__ Wl, const float* __restrict__ Wr, __bf16* __restrict__ out)
{
    int t = blockIdx.x * blockDim.x + threadIdx.x;   // elem index, 256*512
    if (t >= 256 * 512) return;
    int f = t >> 9;          // frag 0..255
    int e = t & 511;
    int l = e >> 3;
    int j = e & 7;
    int ncg = f >> 4;
    int kc  = f & 15;
    int col = ncg * 16 + (l & 15);
    int k   = kc * 32 + (l >> 4) * 8 + j;
    float v = (k < 256) ? Wl[(size_t)k * 256 + col] : Wr[(size_t)(k - 256) * 256 + col];
    out[t] = (__bf16)v;
}

// ---------------------------------------------------------------------------
// Aggregation: one wave per dst row; 2 edges per wave-step (32 lanes x 16B),
// 16 edges in flight; cross-half combine via shfl_xor(32).   (unchanged)
// ---------------------------------------------------------------------------
__global__ __launch_bounds__(256) void aggregate_bf16(
    const __bf16* __restrict__ xsrc, const int* __restrict__ rsrc,
    const float* __restrict__ rw, const int* __restrict__ rowptr,
    __bf16* __restrict__ mean, int ndst)
{
    int wid  = (blockIdx.x * blockDim.x + threadIdx.x) >> 6;
    int lane = threadIdx.x & 63;
    if (wid >= ndst) return;
    int beg = rowptr[wid], end = rowptr[wid + 1];
    const int half = lane >> 5, hl = lane & 31;
    const __bf16* xcol = xsrc + hl * 8;
    float acc[8];
    #pragma unroll
    for (int i = 0; i < 8; ++i) acc[i] = 0.f;

    int j0 = beg;
    while (j0 < end) {
        int m = end - j0; if (m > 64) m = 64;
        int   sl = (lane < m) ? rsrc[j0 + lane] : 0;
        float wl = (lane < m) ? rw[j0 + lane]   : 0.f;
        int t = 0;
        for (; t + 16 <= m; t += 16) {
            bf16x8 v[8]; float wt[8];
            #pragma unroll
            for (int u = 0; u < 8; ++u) {
                int tt = t + u * 2;
                int e0 = __builtin_amdgcn_readlane(sl, tt);
                int e1 = __builtin_amdgcn_readlane(sl, tt + 1);
                int w0 = __builtin_amdgcn_readlane(__float_as_int(wl), tt);
                int w1 = __builtin_amdgcn_readlane(__float_as_int(wl), tt + 1);
                int s = half ? e1 : e0;
                wt[u] = __int_as_float(half ? w1 : w0);
                v[u] = *reinterpret_cast<const bf16x8*>(xcol + (size_t)s * DFEAT);
            }
            #pragma unroll
            for (int u = 0; u < 8; ++u)
                #pragma unroll
                for (int i = 0; i < 8; ++i) acc[i] += wt[u] * (float)v[u][i];
        }
        for (; t < m; t += 2) {
            int e0 = __builtin_amdgcn_readlane(sl, t);
            int e1 = __builtin_amdgcn_readlane(sl, (t + 1 < 64) ? t + 1 : 63);
            int w0 = __builtin_amdgcn_readlane(__float_as_int(wl), t);
            int w1 = __builtin_amdgcn_readlane(__float_as_int(wl), (t + 1 < 64) ? t + 1 : 63);
            int s = half ? e1 : e0;
            float wv2 = __int_as_float(half ? w1 : w0);
            if (half && t + 1 >= m) wv2 = 0.f;
            bf16x8 v = *reinterpret_cast<const bf16x8*>(xcol + (size_t)s * DFEAT);
            #pragma unroll
            for (int i = 0; i < 8; ++i) acc[i] += wv2 * (float)v[i];
        }
        j0 += m;
    }

    #pragma unroll
    for (int i = 0; i < 8; ++i) acc[i] += __shfl_xor(acc[i], 32);
    float inv = (end > beg) ? 1.0f / (float)(end - beg) : 0.0f;
    if (half == 0) {
        bf16x8 o;
        #pragma unroll
        for (int i = 0; i < 8; ++i) o[i] = (__bf16)(acc[i] * inv);
        *reinterpret_cast<bf16x8*>(mean + (size_t)wid * DFEAT + hl * 8) = o;
    }
}

// ---------------------------------------------------------------------------
// MFMA GEMM (R4 structure + packed-B): out[i,:] = epi(A@Wl + B@Wr + bias)
// 256 thr = 4 waves; wave w owns cols [w*64, w*64+64); BM=64 rows/block.
// K=512 as 8 chunks of BK=64 (chunks 0-3 read Amat, 4-7 read Bmat).
// A staged in LDS (double-buffered 2x8KB) via coalesced global_load_lds with
// T2 XOR swizzle; B read per-chunk from PACKED fragment-major WTP: each frag
// is a single fully-coalesced 1KB L2-hot load (no 16-line scatter).
// ---------------------------------------------------------------------------
template<int EPI>
__global__ __launch_bounds__(256) void gemm_mfma(
    const __bf16* __restrict__ Amat, const __bf16* __restrict__ Bmat,
    const __bf16* __restrict__ WTP, const float* __restrict__ bias,
    const __bf16* __restrict__ resid, void* __restrict__ outv, int n)
{
    __shared__ char sA[2][64 * 128];      // [64 rows][64 k] bf16, dbuf = 16 KB

    const int tid  = threadIdx.x;
    const int lane = tid & 63;
    const int wv   = tid >> 6;            // wave = col group
    const int lo   = lane & 15;
    const int hi   = lane >> 4;
    const int brow = blockIdx.x * 64;
    const int wcol = wv * 64;
    const int nm1  = n - 1;

    f32x4 acc[4][4];
    #pragma unroll
    for (int i = 0; i < 4; ++i)
        #pragma unroll
        for (int j = 0; j < 4; ++j) acc[i][j] = (f32x4){0.f, 0.f, 0.f, 0.f};

    auto stage = [&](int chunk, int buf) {
        const __bf16* mat = (chunk < 4) ? Amat : Bmat;
        const int kbyte = (chunk & 3) * 128;
        #pragma unroll
        for (int q = 0; q < 2; ++q) {          // 512 slots of 16B, 2/thread
            int s = q * 256 + tid;
            int r = s >> 3, sub = s & 7;
            int grow = brow + r; if (grow > nm1) grow = nm1;
            int srcoff = (sub * 16) ^ ((r & 7) << 4);
            const char* g = reinterpret_cast<const char*>(mat) + (size_t)grow * 512 + kbyte + srcoff;
            __builtin_amdgcn_global_load_lds(
                (const __attribute__((address_space(1))) void*)g,
                (__attribute__((address_space(3))) void*)(sA[buf] + s * 16), 16, 0, 0);
        }
    };

    const char* Wb = reinterpret_cast<const char*>(WTP);
    const int lb = lane * 16;

    stage(0, 0);
    __syncthreads();

    for (int c = 0; c < 8; ++c) {
        const int cur = c & 1;
        if (c < 7) stage(c + 1, cur ^ 1);
        // B fragments for this chunk: packed, 1KB coalesced each, L2-hot
        bf16x8 bfr[2][4];
        #pragma unroll
        for (int ks = 0; ks < 2; ++ks)
            #pragma unroll
            for (int nn = 0; nn < 4; ++nn)
                bfr[ks][nn] = *reinterpret_cast<const bf16x8*>(
                    Wb + (size_t)(((wv * 4 + nn) * 16 + c * 2 + ks) << 10) + lb);
        #pragma unroll
        for (int ks = 0; ks < 2; ++ks) {
            const int kb = ks * 64 + hi * 16;
            #pragma unroll
            for (int mm = 0; mm < 4; ++mm) {
                int r = mm * 16 + lo;
                bf16x8 a = *reinterpret_cast<const bf16x8*>(
                    sA[cur] + r * 128 + (kb ^ ((r & 7) << 4)));
                #pragma unroll
                for (int nn = 0; nn < 4; ++nn)
                    acc[mm][nn] = __builtin_amdgcn_mfma_f32_16x16x32_bf16(
                        a, bfr[ks][nn], acc[mm][nn], 0, 0, 0);
            }
        }
        __syncthreads();   // drains vmcnt (next chunk staged) + lgkm
    }

    // epilogue: D col = lane&15, row = (lane>>4)*4 + reg
    #pragma unroll
    for (int mm = 0; mm < 4; ++mm) {
        #pragma unroll
        for (int nn = 0; nn < 4; ++nn) {
            int col = wcol + nn * 16 + lo;
            float bv2 = bias[col];
            #pragma unroll
            for (int r = 0; r < 4; ++r) {
                int grow = brow + mm * 16 + hi * 4 + r;
                if (grow >= n) continue;
                float v = acc[mm][nn][r] + bv2;
                if (EPI == 1) {
                    float rv = (float)resid[(size_t)grow * DFEAT + col];
                    ((__bf16*)outv)[(size_t)grow * DFEAT + col] =
                        (__bf16)(rv + fmaxf(v, 0.f));
                } else {
                    ((float*)outv)[(size_t)grow * DFEAT + col] = v;
                }
            }
        }
    }
}

// ---------------------------------------------------------------------------
extern "C" void kernel_launch(void* const* d_in, const int* in_sizes, int n_in,
                              void* d_out, int out_size, void* d_ws, size_t ws_size,
                              hipStream_t stream) {
    const float* x_user  = (const float*)d_in[0];
    const float* x_movie = (const float*)d_in[1];
    const int*   src_um  = (const int*)d_in[2];
    const int*   dst_um  = (const int*)d_in[3];
    const float* w_um    = (const float*)d_in[4];
    const int*   src_mu  = (const int*)d_in[5];
    const int*   dst_mu  = (const int*)d_in[6];
    const float* w_mu    = (const float*)d_in[7];
    const float* c1_um_Wl = (const float*)d_in[8];
    const float* c1_um_Wr = (const float*)d_in[9];
    const float* c1_um_b  = (const float*)d_in[10];
    const float* c1_mu_Wl = (const float*)d_in[11];
    const float* c1_mu_Wr = (const float*)d_in[12];
    const float* c1_mu_b  = (const float*)d_in[13];
    const float* c2_um_Wl = (const float*)d_in[14];
    const float* c2_um_Wr = (const float*)d_in[15];
    const float* c2_um_b  = (const float*)d_in[16];
    const float* c2_mu_Wl = (const float*)d_in[17];
    const float* c2_mu_Wr = (const float*)d_in[18];
    const float* c2_mu_b  = (const float*)d_in[19];

    const int NU = in_sizes[0] / DFEAT;
    const int NM = in_sizes[1] / DFEAT;
    const int E_um = in_sizes[2];
    const int E_mu = in_sizes[5];

    char* p = (char*)d_ws;
    auto carve = [&](size_t bytes) { char* r = p; p += (bytes + 255) & ~(size_t)255; return r; };
    int* rowptr_m = (int*)carve((size_t)(NM + 1) * 4);
    int* rowptr_u = (int*)carve((size_t)(NU + 1) * 4);
    int* cursor_m = (int*)carve((size_t)NM * 4);
    int* cursor_u = (int*)carve((size_t)NU * 4);
    int* bsum_m   = (int*)carve(64 * 4);
    int* bsum_u   = (int*)carve(64 * 4);
    __bf16* xu_bf = (__bf16*)carve((size_t)NU * DFEAT * 2);
    __bf16* xm_bf = (__bf16*)carve((size_t)NM * DFEAT * 2);
    __bf16* ru_bf = (__bf16*)carve((size_t)NU * DFEAT * 2);
    __bf16* rm_bf = (__bf16*)carve((size_t)NM * DFEAT * 2);
    __bf16* wt_c1um = (__bf16*)carve(256 * 512 * 2);
    __bf16* wt_c1mu = (__bf16*)carve(256 * 512 * 2);
    __bf16* wt_c2um = (__bf16*)carve(256 * 512 * 2);
    __bf16* wt_c2mu = (__bf16*)carve(256 * 512 * 2);

    char* dtail = (char*)d_out + (size_t)(NU + NM) * DFEAT * 2;
    int*   rsrc_m = (int*)  (dtail);
    float* rw_m   = (float*)(dtail + (size_t)E_um * 4);
    int*   rsrc_u = (int*)  (dtail + (size_t)E_um * 8);
    float* rw_u   = (float*)(dtail + (size_t)E_um * 8 + (size_t)E_mu * 4);

    __bf16* mean1_u = (__bf16*)d_out;
    __bf16* mean1_m = (__bf16*)d_out + (size_t)NU * DFEAT;
    float* out_user  = (float*)d_out;
    float* out_movie = (float*)d_out + (size_t)NU * DFEAT;

    // ---- CSR build ----
    hipMemsetAsync(rowptr_m, 0, (size_t)(NM + 1) * 4, stream);
    hipMemsetAsync(rowptr_u, 0, (size_t)(NU + 1) * 4, stream);
    hist_kernel<<<2048, 256, 0, stream>>>(dst_um, E_um, rowptr_m);
    hist_kernel<<<2048, 256, 0, stream>>>(dst_mu, E_mu, rowptr_u);
    const int nbM = (NM + 1 + 2047) / 2048;
    const int nbU = (NU + 1 + 2047) / 2048;
    scan_block<<<nbM, 256, 0, stream>>>(rowptr_m, NM + 1, bsum_m);
    scan_block<<<nbU, 256, 0, stream>>>(rowptr_u, NU + 1, bsum_u);
    scan_sums<<<1, 64, 0, stream>>>(bsum_m, nbM);
    scan_sums<<<1, 64, 0, stream>>>(bsum_u, nbU);
    scan_add<<<nbM, 256, 0, stream>>>(rowptr_m, NM + 1, bsum_m);
    scan_add<<<nbU, 256, 0, stream>>>(rowptr_u, NU + 1, bsum_u);
    copy_int<<<256, 256, 0, stream>>>(rowptr_m, cursor_m, NM);
    copy_int<<<256, 256, 0, stream>>>(rowptr_u, cursor_u, NU);
    fill_kernel<<<2048, 256, 0, stream>>>(dst_um, src_um, w_um, E_um, cursor_m, rsrc_m, rw_m);
    fill_kernel<<<2048, 256, 0, stream>>>(dst_mu, src_mu, w_mu, E_mu, cursor_u, rsrc_u, rw_u);

    // ---- bf16 features + packed fragment-major weights ----
    f32_to_bf16_kernel<<<2048, 256, 0, stream>>>(x_user, xu_bf, NU * DFEAT / 8);
    f32_to_bf16_kernel<<<2048, 256, 0, stream>>>(x_movie, xm_bf, NM * DFEAT / 8);
    wtrans_kernel<<<512, 256, 0, stream>>>(c1_um_Wl, c1_um_Wr, wt_c1um);
    wtrans_kernel<<<512, 256, 0, stream>>>(c1_mu_Wl, c1_mu_Wr, wt_c1mu);
    wtrans_kernel<<<512, 256, 0, stream>>>(c2_um_Wl, c2_um_Wr, wt_c2um);
    wtrans_kernel<<<512, 256, 0, stream>>>(c2_mu_Wl, c2_mu_Wr, wt_c2mu);

    // ---- layer 1 ----
    aggregate_bf16<<<(NM + 3) / 4, 256, 0, stream>>>(xu_bf, rsrc_m, rw_m, rowptr_m, mean1_m, NM);
    aggregate_bf16<<<(NU + 3) / 4, 256, 0, stream>>>(xm_bf, rsrc_u, rw_u, rowptr_u, mean1_u, NU);
    gemm_mfma<1><<<(NM + 63) / 64, 256, 0, stream>>>(mean1_m, xm_bf, wt_c1um, c1_um_b, xm_bf, rm_bf, NM);
    gemm_mfma<1><<<(NU + 63) / 64, 256, 0, stream>>>(mean1_u, xu_bf, wt_c1mu, c1_mu_b, xu_bf, ru_bf, NU);

    // ---- layer 2 ----
    __bf16* mean2_m = xm_bf;
    __bf16* mean2_u = xu_bf;
    aggregate_bf16<<<(NM + 3) / 4, 256, 0, stream>>>(ru_bf, rsrc_m, rw_m, rowptr_m, mean2_m, NM);
    aggregate_bf16<<<(NU + 3) / 4, 256, 0, stream>>>(rm_bf, rsrc_u, rw_u, rowptr_u, mean2_u, NU);
    gemm_mfma<0><<<(NM + 63) / 64, 256, 0, stream>>>(mean2_m, rm_bf, wt_c2um, c2_um_b, nullptr, out_movie, NM);
    gemm_mfma<0><<<(NU + 63) / 64, 256, 0, stream>>>(mean2_u, ru_bf, wt_c2mu, c2_mu_b, nullptr, out_user, NU);
}

// Round 10
// 741.120 us; speedup vs baseline: 1.2091x; 1.0054x over previous
//
#include <hip/hip_runtime.h>
#include <hip/hip_bf16.h>

#define DFEAT 256

typedef __bf16 bf16x8 __attribute__((ext_vector_type(8)));
typedef __bf16 bf16x4 __attribute__((ext_vector_type(4)));
typedef float  f32x4  __attribute__((ext_vector_type(4)));

// ---------------------------------------------------------------------------
// CSR build: histogram -> hierarchical scan -> cursor scatter (sorted records)
// ---------------------------------------------------------------------------
__global__ void hist_kernel(const int* __restrict__ dst, int nE, int* __restrict__ P) {
    for (int e = blockIdx.x * blockDim.x + threadIdx.x; e < nE; e += gridDim.x * blockDim.x)
        atomicAdd(&P[dst[e] + 1], 1);
}

__global__ __launch_bounds__(256) void scan_block(int* __restrict__ a, int n, int* __restrict__ bsum) {
    __shared__ int wsum[4];
    const int tid = threadIdx.x;
    const int lane = tid & 63, wv = tid >> 6;
    const int idx = blockIdx.x * 2048 + tid * 8;
    int v[8];
    #pragma unroll
    for (int i = 0; i < 8; ++i) v[i] = (idx + i < n) ? a[idx + i] : 0;
    #pragma unroll
    for (int i = 1; i < 8; ++i) v[i] += v[i - 1];
    int tsum = v[7];
    int sc = tsum;
    #pragma unroll
    for (int off = 1; off < 64; off <<= 1) {
        int t = __shfl_up(sc, off);
        if (lane >= off) sc += t;
    }
    if (lane == 63) wsum[wv] = sc;
    __syncthreads();
    int wadd = 0;
    for (int w2 = 0; w2 < wv; ++w2) wadd += wsum[w2];
    int texcl = sc - tsum + wadd;
    #pragma unroll
    for (int i = 0; i < 8; ++i)
        if (idx + i < n) a[idx + i] = v[i] + texcl;
    if (tid == 255) bsum[blockIdx.x] = sc + wadd;
}

__global__ void scan_sums(int* __restrict__ bsum, int nb) {
    int lane = threadIdx.x;
    int v = (lane < nb) ? bsum[lane] : 0;
    #pragma unroll
    for (int off = 1; off < 64; off <<= 1) {
        int t = __shfl_up(v, off);
        if (lane >= off) v += t;
    }
    if (lane < nb) bsum[lane] = v;
}

__global__ __launch_bounds__(256) void scan_add(int* __restrict__ a, int n, const int* __restrict__ bsum) {
    if (blockIdx.x == 0) return;
    int add = bsum[blockIdx.x - 1];
    int idx = blockIdx.x * 2048 + threadIdx.x * 8;
    #pragma unroll
    for (int i = 0; i < 8; ++i)
        if (idx + i < n) a[idx + i] += add;
}

__global__ void copy_int(const int* __restrict__ src, int* __restrict__ dst, int n) {
    for (int i = blockIdx.x * blockDim.x + threadIdx.x; i < n; i += gridDim.x * blockDim.x)
        dst[i] = src[i];
}

__global__ void fill_kernel(const int* __restrict__ dst, const int* __restrict__ src,
                            const float* __restrict__ w, int nE,
                            int* __restrict__ cursor,
                            int* __restrict__ rsrc, float* __restrict__ rw) {
    for (int e = blockIdx.x * blockDim.x + threadIdx.x; e < nE; e += gridDim.x * blockDim.x) {
        int pos = atomicAdd(&cursor[dst[e]], 1);
        rsrc[pos] = src[e];
        rw[pos]   = w[e];
    }
}

// ---------------------------------------------------------------------------
__global__ __launch_bounds__(256) void f32_to_bf16_kernel(
    const float* __restrict__ in, __bf16* __restrict__ out, int n8)
{
    for (int i = blockIdx.x * blockDim.x + threadIdx.x; i < n8; i += gridDim.x * blockDim.x) {
        float4 a = *reinterpret_cast<const float4*>(in + (size_t)i * 8);
        float4 b = *reinterpret_cast<const float4*>(in + (size_t)i * 8 + 4);
        bf16x8 v;
        v[0] = (__bf16)a.x; v[1] = (__bf16)a.y; v[2] = (__bf16)a.z; v[3] = (__bf16)a.w;
        v[4] = (__bf16)b.x; v[5] = (__bf16)b.y; v[6] = (__bf16)b.z; v[7] = (__bf16)b.w;
        *reinterpret_cast<bf16x8*>(out + (size_t)i * 8) = v;
    }
}

// Packed fragment-major weights: frag f = ncg*16 + kc; lane l holds 8 bf16 at
// byte f*1024 + l*16: value[j] = Wcat[k = kc*32 + (l>>4)*8 + j][col = ncg*16 + (l&15)]
// (Wcat rows 0..255 = Wl, 256..511 = Wr). B-frag loads are 1KB coalesced reads.
__global__ __launch_bounds__(256) void wtrans_kernel(
    const float* __restrict__ Wl, const float* __restrict__ Wr, __bf16* __restrict__ out)
{
    int t = blockIdx.x * blockDim.x + threadIdx.x;   // elem index, 256*512
    if (t >= 256 * 512) return;
    int f = t >> 9;          // frag 0..255
    int e = t & 511;
    int l = e >> 3;
    int j = e & 7;
    int ncg = f >> 4;
    int kc  = f & 15;
    int col = ncg * 16 + (l & 15);
    int k   = kc * 32 + (l >> 4) * 8 + j;
    float v = (k < 256) ? Wl[(size_t)k * 256 + col] : Wr[(size_t)(k - 256) * 256 + col];
    out[t] = (__bf16)v;
}

// ---------------------------------------------------------------------------
// Aggregation: one wave per dst row; 2 edges per wave-step (32 lanes x 16B),
// 16 edges in flight; cross-half combine via shfl_xor(32).   (unchanged)
// ---------------------------------------------------------------------------
__global__ __launch_bounds__(256) void aggregate_bf16(
    const __bf16* __restrict__ xsrc, const int* __restrict__ rsrc,
    const float* __restrict__ rw, const int* __restrict__ rowptr,
    __bf16* __restrict__ mean, int ndst)
{
    int wid  = (blockIdx.x * blockDim.x + threadIdx.x) >> 6;
    int lane = threadIdx.x & 63;
    if (wid >= ndst) return;
    int beg = rowptr[wid], end = rowptr[wid + 1];
    const int half = lane >> 5, hl = lane & 31;
    const __bf16* xcol = xsrc + hl * 8;
    float acc[8];
    #pragma unroll
    for (int i = 0; i < 8; ++i) acc[i] = 0.f;

    int j0 = beg;
    while (j0 < end) {
        int m = end - j0; if (m > 64) m = 64;
        int   sl = (lane < m) ? rsrc[j0 + lane] : 0;
        float wl = (lane < m) ? rw[j0 + lane]   : 0.f;
        int t = 0;
        for (; t + 16 <= m; t += 16) {
            bf16x8 v[8]; float wt[8];
            #pragma unroll
            for (int u = 0; u < 8; ++u) {
                int tt = t + u * 2;
                int e0 = __builtin_amdgcn_readlane(sl, tt);
                int e1 = __builtin_amdgcn_readlane(sl, tt + 1);
                int w0 = __builtin_amdgcn_readlane(__float_as_int(wl), tt);
                int w1 = __builtin_amdgcn_readlane(__float_as_int(wl), tt + 1);
                int s = half ? e1 : e0;
                wt[u] = __int_as_float(half ? w1 : w0);
                v[u] = *reinterpret_cast<const bf16x8*>(xcol + (size_t)s * DFEAT);
            }
            #pragma unroll
            for (int u = 0; u < 8; ++u)
                #pragma unroll
                for (int i = 0; i < 8; ++i) acc[i] += wt[u] * (float)v[u][i];
        }
        for (; t < m; t += 2) {
            int e0 = __builtin_amdgcn_readlane(sl, t);
            int e1 = __builtin_amdgcn_readlane(sl, (t + 1 < 64) ? t + 1 : 63);
            int w0 = __builtin_amdgcn_readlane(__float_as_int(wl), t);
            int w1 = __builtin_amdgcn_readlane(__float_as_int(wl), (t + 1 < 64) ? t + 1 : 63);
            int s = half ? e1 : e0;
            float wv2 = __int_as_float(half ? w1 : w0);
            if (half && t + 1 >= m) wv2 = 0.f;
            bf16x8 v = *reinterpret_cast<const bf16x8*>(xcol + (size_t)s * DFEAT);
            #pragma unroll
            for (int i = 0; i < 8; ++i) acc[i] += wv2 * (float)v[i];
        }
        j0 += m;
    }

    #pragma unroll
    for (int i = 0; i < 8; ++i) acc[i] += __shfl_xor(acc[i], 32);
    float inv = (end > beg) ? 1.0f / (float)(end - beg) : 0.0f;
    if (half == 0) {
        bf16x8 o;
        #pragma unroll
        for (int i = 0; i < 8; ++i) o[i] = (__bf16)(acc[i] * inv);
        *reinterpret_cast<bf16x8*>(mean + (size_t)wid * DFEAT + hl * 8) = o;
    }
}

// ---------------------------------------------------------------------------
// MFMA GEMM, counted-drain pipeline: out[i,:] = epi(A@Wl + B@Wr + bias)
// 256 thr = 4 waves; wave w owns cols [w*64,+64); BM=64. K=512 = 8 chunks of 64
// (chunks 0-3 read Amat, 4-7 read Bmat). A LDS-staged (2x8KB dbuf, T2 swizzle);
// B from packed fragment-major WTP (1KB coalesced L2-hot loads).
// Pipeline: the only vmcnt(0) drain sits ONE FULL ITERATION after the stage
// issue (top-of-loop), so stage(c) latency hides under iter c-1's B-wait+MFMA.
// Issue order B(c) THEN stage(c+1) => compiler's pre-MFMA wait is vmcnt(2),
// keeping the prefetch in flight. Raw s_barrier (no implicit drain).
// WAR safety: stage(c+1) is issued post-barrier_c; all waves' ds_reads of
// buf^1 (iter c-1) are lgkm-complete before they reach barrier_c.
// ---------------------------------------------------------------------------
template<int EPI>
__global__ __launch_bounds__(256) void gemm_mfma(
    const __bf16* __restrict__ Amat, const __bf16* __restrict__ Bmat,
    const __bf16* __restrict__ WTP, const float* __restrict__ bias,
    const __bf16* __restrict__ resid, void* __restrict__ outv, int n)
{
    __shared__ char sA[2][64 * 128];      // [64 rows][64 k] bf16, dbuf = 16 KB

    const int tid  = threadIdx.x;
    const int lane = tid & 63;
    const int wv   = tid >> 6;            // wave = col group
    const int lo   = lane & 15;
    const int hi   = lane >> 4;
    const int brow = blockIdx.x * 64;
    const int wcol = wv * 64;
    const int nm1  = n - 1;

    f32x4 acc[4][4];
    #pragma unroll
    for (int i = 0; i < 4; ++i)
        #pragma unroll
        for (int j = 0; j < 4; ++j) acc[i][j] = (f32x4){0.f, 0.f, 0.f, 0.f};

    auto stage = [&](int chunk, int buf) {
        const __bf16* mat = (chunk < 4) ? Amat : Bmat;
        const int kbyte = (chunk & 3) * 128;
        #pragma unroll
        for (int q = 0; q < 2; ++q) {          // 512 slots of 16B, 2/thread
            int s = q * 256 + tid;
            int r = s >> 3, sub = s & 7;
            int grow = brow + r; if (grow > nm1) grow = nm1;
            int srcoff = (sub * 16) ^ ((r & 7) << 4);
            const char* g = reinterpret_cast<const char*>(mat) + (size_t)grow * 512 + kbyte + srcoff;
            __builtin_amdgcn_global_load_lds(
                (const __attribute__((address_space(1))) void*)g,
                (__attribute__((address_space(3))) void*)(sA[buf] + s * 16), 16, 0, 0);
        }
    };

    const char* Wb = reinterpret_cast<const char*>(WTP);
    const int lb = lane * 16;

    stage(0, 0);

    for (int c = 0; c < 8; ++c) {
        const int cur = c & 1;
        // drain stage(c) (issued one full iteration ago) — residual latency only
        asm volatile("s_waitcnt vmcnt(0)" ::: "memory");
        __builtin_amdgcn_s_barrier();
        __builtin_amdgcn_sched_barrier(0);
        // B fragments first (so compiler's pre-MFMA wait is vmcnt(2), not 0)
        bf16x8 bfr[2][4];
        #pragma unroll
        for (int ks = 0; ks < 2; ++ks)
            #pragma unroll
            for (int nn = 0; nn < 4; ++nn)
                bfr[ks][nn] = *reinterpret_cast<const bf16x8*>(
                    Wb + (size_t)(((wv * 4 + nn) * 16 + c * 2 + ks) << 10) + lb);
        // prefetch next chunk into the other buffer (drained at next iter top)
        if (c < 7) stage(c + 1, cur ^ 1);
        #pragma unroll
        for (int ks = 0; ks < 2; ++ks) {
            const int kb = ks * 64 + hi * 16;
            #pragma unroll
            for (int mm = 0; mm < 4; ++mm) {
                int r = mm * 16 + lo;
                bf16x8 a = *reinterpret_cast<const bf16x8*>(
                    sA[cur] + r * 128 + (kb ^ ((r & 7) << 4)));
                #pragma unroll
                for (int nn = 0; nn < 4; ++nn)
                    acc[mm][nn] = __builtin_amdgcn_mfma_f32_16x16x32_bf16(
                        a, bfr[ks][nn], acc[mm][nn], 0, 0, 0);
            }
        }
    }

    // epilogue: D col = lane&15, row = (lane>>4)*4 + reg
    #pragma unroll
    for (int mm = 0; mm < 4; ++mm) {
        #pragma unroll
        for (int nn = 0; nn < 4; ++nn) {
            int col = wcol + nn * 16 + lo;
            float bv2 = bias[col];
            #pragma unroll
            for (int r = 0; r < 4; ++r) {
                int grow = brow + mm * 16 + hi * 4 + r;
                if (grow >= n) continue;
                float v = acc[mm][nn][r] + bv2;
                if (EPI == 1) {
                    float rv = (float)resid[(size_t)grow * DFEAT + col];
                    ((__bf16*)outv)[(size_t)grow * DFEAT + col] =
                        (__bf16)(rv + fmaxf(v, 0.f));
                } else {
                    ((float*)outv)[(size_t)grow * DFEAT + col] = v;
                }
            }
        }
    }
}

// ---------------------------------------------------------------------------
extern "C" void kernel_launch(void* const* d_in, const int* in_sizes, int n_in,
                              void* d_out, int out_size, void* d_ws, size_t ws_size,
                              hipStream_t stream) {
    const float* x_user  = (const float*)d_in[0];
    const float* x_movie = (const float*)d_in[1];
    const int*   src_um  = (const int*)d_in[2];
    const int*   dst_um  = (const int*)d_in[3];
    const float* w_um    = (const float*)d_in[4];
    const int*   src_mu  = (const int*)d_in[5];
    const int*   dst_mu  = (const int*)d_in[6];
    const float* w_mu    = (const float*)d_in[7];
    const float* c1_um_Wl = (const float*)d_in[8];
    const float* c1_um_Wr = (const float*)d_in[9];
    const float* c1_um_b  = (const float*)d_in[10];
    const float* c1_mu_Wl = (const float*)d_in[11];
    const float* c1_mu_Wr = (const float*)d_in[12];
    const float* c1_mu_b  = (const float*)d_in[13];
    const float* c2_um_Wl = (const float*)d_in[14];
    const float* c2_um_Wr = (const float*)d_in[15];
    const float* c2_um_b  = (const float*)d_in[16];
    const float* c2_mu_Wl = (const float*)d_in[17];
    const float* c2_mu_Wr = (const float*)d_in[18];
    const float* c2_mu_b  = (const float*)d_in[19];

    const int NU = in_sizes[0] / DFEAT;
    const int NM = in_sizes[1] / DFEAT;
    const int E_um = in_sizes[2];
    const int E_mu = in_sizes[5];

    char* p = (char*)d_ws;
    auto carve = [&](size_t bytes) { char* r = p; p += (bytes + 255) & ~(size_t)255; return r; };
    int* rowptr_m = (int*)carve((size_t)(NM + 1) * 4);
    int* rowptr_u = (int*)carve((size_t)(NU + 1) * 4);
    int* cursor_m = (int*)carve((size_t)NM * 4);
    int* cursor_u = (int*)carve((size_t)NU * 4);
    int* bsum_m   = (int*)carve(64 * 4);
    int* bsum_u   = (int*)carve(64 * 4);
    __bf16* xu_bf = (__bf16*)carve((size_t)NU * DFEAT * 2);
    __bf16* xm_bf = (__bf16*)carve((size_t)NM * DFEAT * 2);
    __bf16* ru_bf = (__bf16*)carve((size_t)NU * DFEAT * 2);
    __bf16* rm_bf = (__bf16*)carve((size_t)NM * DFEAT * 2);
    __bf16* wt_c1um = (__bf16*)carve(256 * 512 * 2);
    __bf16* wt_c1mu = (__bf16*)carve(256 * 512 * 2);
    __bf16* wt_c2um = (__bf16*)carve(256 * 512 * 2);
    __bf16* wt_c2mu = (__bf16*)carve(256 * 512 * 2);

    char* dtail = (char*)d_out + (size_t)(NU + NM) * DFEAT * 2;
    int*   rsrc_m = (int*)  (dtail);
    float* rw_m   = (float*)(dtail + (size_t)E_um * 4);
    int*   rsrc_u = (int*)  (dtail + (size_t)E_um * 8);
    float* rw_u   = (float*)(dtail + (size_t)E_um * 8 + (size_t)E_mu * 4);

    __bf16* mean1_u = (__bf16*)d_out;
    __bf16* mean1_m = (__bf16*)d_out + (size_t)NU * DFEAT;
    float* out_user  = (float*)d_out;
    float* out_movie = (float*)d_out + (size_t)NU * DFEAT;

    // ---- CSR build ----
    hipMemsetAsync(rowptr_m, 0, (size_t)(NM + 1) * 4, stream);
    hipMemsetAsync(rowptr_u, 0, (size_t)(NU + 1) * 4, stream);
    hist_kernel<<<2048, 256, 0, stream>>>(dst_um, E_um, rowptr_m);
    hist_kernel<<<2048, 256, 0, stream>>>(dst_mu, E_mu, rowptr_u);
    const int nbM = (NM + 1 + 2047) / 2048;
    const int nbU = (NU + 1 + 2047) / 2048;
    scan_block<<<nbM, 256, 0, stream>>>(rowptr_m, NM + 1, bsum_m);
    scan_block<<<nbU, 256, 0, stream>>>(rowptr_u, NU + 1, bsum_u);
    scan_sums<<<1, 64, 0, stream>>>(bsum_m, nbM);
    scan_sums<<<1, 64, 0, stream>>>(bsum_u, nbU);
    scan_add<<<nbM, 256, 0, stream>>>(rowptr_m, NM + 1, bsum_m);
    scan_add<<<nbU, 256, 0, stream>>>(rowptr_u, NU + 1, bsum_u);
    copy_int<<<256, 256, 0, stream>>>(rowptr_m, cursor_m, NM);
    copy_int<<<256, 256, 0, stream>>>(rowptr_u, cursor_u, NU);
    fill_kernel<<<2048, 256, 0, stream>>>(dst_um, src_um, w_um, E_um, cursor_m, rsrc_m, rw_m);
    fill_kernel<<<2048, 256, 0, stream>>>(dst_mu, src_mu, w_mu, E_mu, cursor_u, rsrc_u, rw_u);

    // ---- bf16 features + packed fragment-major weights ----
    f32_to_bf16_kernel<<<2048, 256, 0, stream>>>(x_user, xu_bf, NU * DFEAT / 8);
    f32_to_bf16_kernel<<<2048, 256, 0, stream>>>(x_movie, xm_bf, NM * DFEAT / 8);
    wtrans_kernel<<<512, 256, 0, stream>>>(c1_um_Wl, c1_um_Wr, wt_c1um);
    wtrans_kernel<<<512, 256, 0, stream>>>(c1_mu_Wl, c1_mu_Wr, wt_c1mu);
    wtrans_kernel<<<512, 256, 0, stream>>>(c2_um_Wl, c2_um_Wr, wt_c2um);
    wtrans_kernel<<<512, 256, 0, stream>>>(c2_mu_Wl, c2_mu_Wr, wt_c2mu);

    // ---- layer 1 ----
    aggregate_bf16<<<(NM + 3) / 4, 256, 0, stream>>>(xu_bf, rsrc_m, rw_m, rowptr_m, mean1_m, NM);
    aggregate_bf16<<<(NU + 3) / 4, 256, 0, stream>>>(xm_bf, rsrc_u, rw_u, rowptr_u, mean1_u, NU);
    gemm_mfma<1><<<(NM + 63) / 64, 256, 0, stream>>>(mean1_m, xm_bf, wt_c1um, c1_um_b, xm_bf, rm_bf, NM);
    gemm_mfma<1><<<(NU + 63) / 64, 256, 0, stream>>>(mean1_u, xu_bf, wt_c1mu, c1_mu_b, xu_bf, ru_bf, NU);

    // ---- layer 2 ----
    __bf16* mean2_m = xm_bf;
    __bf16* mean2_u = xu_bf;
    aggregate_bf16<<<(NM + 3) / 4, 256, 0, stream>>>(ru_bf, rsrc_m, rw_m, rowptr_m, mean2_m, NM);
    aggregate_bf16<<<(NU + 3) / 4, 256, 0, stream>>>(rm_bf, rsrc_u, rw_u, rowptr_u, mean2_u, NU);
    gemm_mfma<0><<<(NM + 63) / 64, 256, 0, stream>>>(mean2_m, rm_bf, wt_c2um, c2_um_b, nullptr, out_movie, NM);
    gemm_mfma<0><<<(NU + 63) / 64, 256, 0, stream>>>(mean2_u, ru_bf, wt_c2mu, c2_mu_b, nullptr, out_user, NU);
}

// Round 11
// 693.520 us; speedup vs baseline: 1.2921x; 1.0686x over previous
//
#include <hip/hip_runtime.h>
#include <hip/hip_bf16.h>

#define DFEAT 256

typedef __bf16 bf16x8 __attribute__((ext_vector_type(8)));
typedef __bf16 bf16x4 __attribute__((ext_vector_type(4)));
typedef float  f32x4  __attribute__((ext_vector_type(4)));

// ---------------------------------------------------------------------------
// CSR build (merged kernels): histogram -> hierarchical scan -> cursor scatter
// ---------------------------------------------------------------------------
__global__ void hist2_kernel(const int* __restrict__ dA, int nA, int* __restrict__ PA,
                             const int* __restrict__ dB, int nB, int* __restrict__ PB) {
    int half = gridDim.x >> 1;
    if (blockIdx.x < half) {
        for (int e = blockIdx.x * blockDim.x + threadIdx.x; e < nA; e += half * blockDim.x)
            atomicAdd(&PA[dA[e] + 1], 1);
    } else {
        for (int e = (blockIdx.x - half) * blockDim.x + threadIdx.x; e < nB; e += half * blockDim.x)
            atomicAdd(&PB[dB[e] + 1], 1);
    }
}

__global__ __launch_bounds__(256) void scan_block2(
    int* __restrict__ am, int nm, int* __restrict__ bsm,
    int* __restrict__ au, int nu, int* __restrict__ bsu, int nbM)
{
    __shared__ int wsum[4];
    int* a; int n; int* bsum; int bid;
    if ((int)blockIdx.x < nbM) { a = am; n = nm; bsum = bsm; bid = blockIdx.x; }
    else                       { a = au; n = nu; bsum = bsu; bid = blockIdx.x - nbM; }
    const int tid = threadIdx.x;
    const int lane = tid & 63, wv = tid >> 6;
    const int idx = bid * 2048 + tid * 8;
    int v[8];
    #pragma unroll
    for (int i = 0; i < 8; ++i) v[i] = (idx + i < n) ? a[idx + i] : 0;
    #pragma unroll
    for (int i = 1; i < 8; ++i) v[i] += v[i - 1];
    int tsum = v[7];
    int sc = tsum;
    #pragma unroll
    for (int off = 1; off < 64; off <<= 1) {
        int t = __shfl_up(sc, off);
        if (lane >= off) sc += t;
    }
    if (lane == 63) wsum[wv] = sc;
    __syncthreads();
    int wadd = 0;
    for (int w2 = 0; w2 < wv; ++w2) wadd += wsum[w2];
    int texcl = sc - tsum + wadd;
    #pragma unroll
    for (int i = 0; i < 8; ++i)
        if (idx + i < n) a[idx + i] = v[i] + texcl;
    if (tid == 255) bsum[bid] = sc + wadd;
}

__global__ void scan_sums2(int* __restrict__ bsm, int nbM, int* __restrict__ bsu, int nbU) {
    int wv = threadIdx.x >> 6;
    int lane = threadIdx.x & 63;
    int* bs = wv ? bsu : bsm;
    int nb  = wv ? nbU : nbM;
    int v = (lane < nb) ? bs[lane] : 0;
    #pragma unroll
    for (int off = 1; off < 64; off <<= 1) {
        int t = __shfl_up(v, off);
        if (lane >= off) v += t;
    }
    if (lane < nb) bs[lane] = v;
}

__global__ __launch_bounds__(256) void scan_add2(
    int* __restrict__ am, int nm, const int* __restrict__ bsm,
    int* __restrict__ au, int nu, const int* __restrict__ bsu, int nbM)
{
    int* a; int n; const int* bsum; int bid;
    if ((int)blockIdx.x < nbM) { a = am; n = nm; bsum = bsm; bid = blockIdx.x; }
    else                       { a = au; n = nu; bsum = bsu; bid = blockIdx.x - nbM; }
    if (bid == 0) return;
    int add = bsum[bid - 1];
    int idx = bid * 2048 + threadIdx.x * 8;
    #pragma unroll
    for (int i = 0; i < 8; ++i)
        if (idx + i < n) a[idx + i] += add;
}

__global__ void copy2_kernel(const int* __restrict__ sA, int* __restrict__ dA, int nA,
                             const int* __restrict__ sB, int* __restrict__ dB, int nB) {
    int total = nA + nB;
    for (int i = blockIdx.x * blockDim.x + threadIdx.x; i < total; i += gridDim.x * blockDim.x) {
        if (i < nA) dA[i] = sA[i];
        else        dB[i - nA] = sB[i - nA];
    }
}

__global__ void fill2_kernel(const int* __restrict__ dstA, const int* __restrict__ srcA,
                             const float* __restrict__ wA, int nA,
                             int* __restrict__ curA, int* __restrict__ rsA, float* __restrict__ rwA,
                             const int* __restrict__ dstB, const int* __restrict__ srcB,
                             const float* __restrict__ wB, int nB,
                             int* __restrict__ curB, int* __restrict__ rsB, float* __restrict__ rwB) {
    int half = gridDim.x >> 1;
    if (blockIdx.x < half) {
        for (int e = blockIdx.x * blockDim.x + threadIdx.x; e < nA; e += half * blockDim.x) {
            int pos = atomicAdd(&curA[dstA[e]], 1);
            rsA[pos] = srcA[e];
            rwA[pos] = wA[e];
        }
    } else {
        for (int e = (blockIdx.x - half) * blockDim.x + threadIdx.x; e < nB; e += half * blockDim.x) {
            int pos = atomicAdd(&curB[dstB[e]], 1);
            rsB[pos] = srcB[e];
            rwB[pos] = wB[e];
        }
    }
}

// ---------------------------------------------------------------------------
__global__ __launch_bounds__(256) void f32_to_bf16_2(
    const float* __restrict__ a, __bf16* __restrict__ oa, int n8a,
    const float* __restrict__ b, __bf16* __restrict__ ob, int n8b)
{
    int total = n8a + n8b;
    for (int i = blockIdx.x * blockDim.x + threadIdx.x; i < total; i += gridDim.x * blockDim.x) {
        const float* in; __bf16* out; int j;
        if (i < n8a) { in = a; out = oa; j = i; }
        else         { in = b; out = ob; j = i - n8a; }
        float4 x = *reinterpret_cast<const float4*>(in + (size_t)j * 8);
        float4 y = *reinterpret_cast<const float4*>(in + (size_t)j * 8 + 4);
        bf16x8 v;
        v[0] = (__bf16)x.x; v[1] = (__bf16)x.y; v[2] = (__bf16)x.z; v[3] = (__bf16)x.w;
        v[4] = (__bf16)y.x; v[5] = (__bf16)y.y; v[6] = (__bf16)y.z; v[7] = (__bf16)y.w;
        *reinterpret_cast<bf16x8*>(out + (size_t)j * 8) = v;
    }
}

// Packed fragment-major weights (4 sets in one launch): frag f = ncg*16 + kc;
// lane l holds 8 bf16 at byte f*1024 + l*16:
// value[j] = Wcat[k = kc*32 + (l>>4)*8 + j][col = ncg*16 + (l&15)]
struct WPack {
    const float* Wl[4];
    const float* Wr[4];
    __bf16* out[4];
};
__global__ __launch_bounds__(256) void wtrans4_kernel(WPack p) {
    int t = blockIdx.x * blockDim.x + threadIdx.x;   // 4 * 131072
    int set = t >> 17;
    int e2  = t & 131071;
    int f = e2 >> 9;
    int e = e2 & 511;
    int l = e >> 3;
    int j = e & 7;
    int ncg = f >> 4;
    int kc  = f & 15;
    int col = ncg * 16 + (l & 15);
    int k   = kc * 32 + (l >> 4) * 8 + j;
    float v = (k < 256) ? p.Wl[set][(size_t)k * 256 + col]
                        : p.Wr[set][(size_t)(k - 256) * 256 + col];
    p.out[set][e2] = (__bf16)v;
}

// ---------------------------------------------------------------------------
// Aggregation: one wave per dst row; 2 edges per wave-step (32 lanes x 16B),
// 16 edges in flight; cross-half combine via shfl_xor(32).   (unchanged)
// ---------------------------------------------------------------------------
__global__ __launch_bounds__(256) void aggregate_bf16(
    const __bf16* __restrict__ xsrc, const int* __restrict__ rsrc,
    const float* __restrict__ rw, const int* __restrict__ rowptr,
    __bf16* __restrict__ mean, int ndst)
{
    int wid  = (blockIdx.x * blockDim.x + threadIdx.x) >> 6;
    int lane = threadIdx.x & 63;
    if (wid >= ndst) return;
    int beg = rowptr[wid], end = rowptr[wid + 1];
    const int half = lane >> 5, hl = lane & 31;
    const __bf16* xcol = xsrc + hl * 8;
    float acc[8];
    #pragma unroll
    for (int i = 0; i < 8; ++i) acc[i] = 0.f;

    int j0 = beg;
    while (j0 < end) {
        int m = end - j0; if (m > 64) m = 64;
        int   sl = (lane < m) ? rsrc[j0 + lane] : 0;
        float wl = (lane < m) ? rw[j0 + lane]   : 0.f;
        int t = 0;
        for (; t + 16 <= m; t += 16) {
            bf16x8 v[8]; float wt[8];
            #pragma unroll
            for (int u = 0; u < 8; ++u) {
                int tt = t + u * 2;
                int e0 = __builtin_amdgcn_readlane(sl, tt);
                int e1 = __builtin_amdgcn_readlane(sl, tt + 1);
                int w0 = __builtin_amdgcn_readlane(__float_as_int(wl), tt);
                int w1 = __builtin_amdgcn_readlane(__float_as_int(wl), tt + 1);
                int s = half ? e1 : e0;
                wt[u] = __int_as_float(half ? w1 : w0);
                v[u] = *reinterpret_cast<const bf16x8*>(xcol + (size_t)s * DFEAT);
            }
            #pragma unroll
            for (int u = 0; u < 8; ++u)
                #pragma unroll
                for (int i = 0; i < 8; ++i) acc[i] += wt[u] * (float)v[u][i];
        }
        for (; t < m; t += 2) {
            int e0 = __builtin_amdgcn_readlane(sl, t);
            int e1 = __builtin_amdgcn_readlane(sl, (t + 1 < 64) ? t + 1 : 63);
            int w0 = __builtin_amdgcn_readlane(__float_as_int(wl), t);
            int w1 = __builtin_amdgcn_readlane(__float_as_int(wl), (t + 1 < 64) ? t + 1 : 63);
            int s = half ? e1 : e0;
            float wv2 = __int_as_float(half ? w1 : w0);
            if (half && t + 1 >= m) wv2 = 0.f;
            bf16x8 v = *reinterpret_cast<const bf16x8*>(xcol + (size_t)s * DFEAT);
            #pragma unroll
            for (int i = 0; i < 8; ++i) acc[i] += wv2 * (float)v[i];
        }
        j0 += m;
    }

    #pragma unroll
    for (int i = 0; i < 8; ++i) acc[i] += __shfl_xor(acc[i], 32);
    float inv = (end > beg) ? 1.0f / (float)(end - beg) : 0.0f;
    if (half == 0) {
        bf16x8 o;
        #pragma unroll
        for (int i = 0; i < 8; ++i) o[i] = (__bf16)(acc[i] * inv);
        *reinterpret_cast<bf16x8*>(mean + (size_t)wid * DFEAT + hl * 8) = o;
    }
}

// ---------------------------------------------------------------------------
// MFMA GEMM, 2-deep pipeline: out[i,:] = epi(A@Wl + B@Wr + bias)
// 256 thr = 4 waves; wave w owns cols [w*64,+64); BM=64. K=512 = 8 chunks of 64
// (chunks 0-3 read Amat, 4-7 read Bmat).
//  - A: 3 LDS buffers, stage(c+2) issued in iter c  -> 2 iterations of cover.
//  - B: packed fragment-major WTP, double-buffered in REGISTERS, loadB(c+1)
//    issued in iter c -> 1 iteration of cover.
//  - Per-iteration VMEM: stage=2 loads, B=8 loads. Issue order within iter:
//    stage(c+2) then loadB(c+1) then MFMA. Compiler's pre-MFMA wait for
//    B(c) (issued last iter) is vmcnt(10) -> stage(c+2)+B(c+1) stay in flight.
//  - The hand vmcnt(10) before each barrier guarantees stage(c) (and all
//    older loads) complete before post-barrier ds_reads, while never draining
//    the 2-ahead prefetch.  WAR: stage(c+2) writes buf[(c-1)%3], whose readers
//    finished (lgkm waits precede their MFMAs) before reaching barrier_c.
// ---------------------------------------------------------------------------
template<int EPI>
__global__ __launch_bounds__(256) void gemm_mfma(
    const __bf16* __restrict__ Amat, const __bf16* __restrict__ Bmat,
    const __bf16* __restrict__ WTP, const float* __restrict__ bias,
    const __bf16* __restrict__ resid, void* __restrict__ outv, int n)
{
    __shared__ char sA[3][64 * 128];      // 3 x 8 KB

    const int tid  = threadIdx.x;
    const int lane = tid & 63;
    const int wv   = tid >> 6;            // wave = col group
    const int lo   = lane & 15;
    const int hi   = lane >> 4;
    const int brow = blockIdx.x * 64;
    const int wcol = wv * 64;
    const int nm1  = n - 1;

    f32x4 acc[4][4];
    #pragma unroll
    for (int i = 0; i < 4; ++i)
        #pragma unroll
        for (int j = 0; j < 4; ++j) acc[i][j] = (f32x4){0.f, 0.f, 0.f, 0.f};

    auto stage = [&](int chunk, int buf) {
        const __bf16* mat = (chunk < 4) ? Amat : Bmat;
        const int kbyte = (chunk & 3) * 128;
        #pragma unroll
        for (int q = 0; q < 2; ++q) {          // 512 slots of 16B, 2/thread
            int s = q * 256 + tid;
            int r = s >> 3, sub = s & 7;
            int grow = brow + r; if (grow > nm1) grow = nm1;
            int srcoff = (sub * 16) ^ ((r & 7) << 4);
            const char* g = reinterpret_cast<const char*>(mat) + (size_t)grow * 512 + kbyte + srcoff;
            __builtin_amdgcn_global_load_lds(
                (const __attribute__((address_space(1))) void*)g,
                (__attribute__((address_space(3))) void*)(sA[buf] + s * 16), 16, 0, 0);
        }
    };

    const char* Wb = reinterpret_cast<const char*>(WTP);
    const int lb = lane * 16;

    bf16x8 bqA[2][4], bqB[2][4];
    auto loadB = [&](int chunk, bf16x8 (&dst)[2][4]) {
        #pragma unroll
        for (int ks = 0; ks < 2; ++ks)
            #pragma unroll
            for (int nn = 0; nn < 4; ++nn)
                dst[ks][nn] = *reinterpret_cast<const bf16x8*>(
                    Wb + (size_t)(((wv * 4 + nn) * 16 + chunk * 2 + ks) << 10) + lb);
    };

    // prologue: 2 stages + first B set in flight
    stage(0, 0);
    stage(1, 1);
    loadB(0, bqA);

    #pragma unroll
    for (int c = 0; c < 8; ++c) {
        // ensure stage(c) (and all older VMEM) done; keep newest 10
        // (stage(c+1)=2 + B(c)=8) in flight
        asm volatile("s_waitcnt vmcnt(10)" ::: "memory");
        __builtin_amdgcn_s_barrier();
        __builtin_amdgcn_sched_barrier(0);
        if (c < 6) stage(c + 2, (c + 2) % 3);
        const int cur = c % 3;
        auto compute = [&](bf16x8 (&bq)[2][4]) {
            #pragma unroll
            for (int ks = 0; ks < 2; ++ks) {
                const int kb = ks * 64 + hi * 16;
                #pragma unroll
                for (int mm = 0; mm < 4; ++mm) {
                    int r = mm * 16 + lo;
                    bf16x8 a = *reinterpret_cast<const bf16x8*>(
                        sA[cur] + r * 128 + (kb ^ ((r & 7) << 4)));
                    #pragma unroll
                    for (int nn = 0; nn < 4; ++nn)
                        acc[mm][nn] = __builtin_amdgcn_mfma_f32_16x16x32_bf16(
                            a, bq[ks][nn], acc[mm][nn], 0, 0, 0);
                }
            }
        };
        if ((c & 1) == 0) { if (c < 7) loadB(c + 1, bqB); compute(bqA); }
        else              { if (c < 7) loadB(c + 1, bqA); compute(bqB); }
    }

    // epilogue: D col = lane&15, row = (lane>>4)*4 + reg
    #pragma unroll
    for (int mm = 0; mm < 4; ++mm) {
        #pragma unroll
        for (int nn = 0; nn < 4; ++nn) {
            int col = wcol + nn * 16 + lo;
            float bv2 = bias[col];
            #pragma unroll
            for (int r = 0; r < 4; ++r) {
                int grow = brow + mm * 16 + hi * 4 + r;
                if (grow >= n) continue;
                float v = acc[mm][nn][r] + bv2;
                if (EPI == 1) {
                    float rv = (float)resid[(size_t)grow * DFEAT + col];
                    ((__bf16*)outv)[(size_t)grow * DFEAT + col] =
                        (__bf16)(rv + fmaxf(v, 0.f));
                } else {
                    ((float*)outv)[(size_t)grow * DFEAT + col] = v;
                }
            }
        }
    }
}

// ---------------------------------------------------------------------------
extern "C" void kernel_launch(void* const* d_in, const int* in_sizes, int n_in,
                              void* d_out, int out_size, void* d_ws, size_t ws_size,
                              hipStream_t stream) {
    const float* x_user  = (const float*)d_in[0];
    const float* x_movie = (const float*)d_in[1];
    const int*   src_um  = (const int*)d_in[2];
    const int*   dst_um  = (const int*)d_in[3];
    const float* w_um    = (const float*)d_in[4];
    const int*   src_mu  = (const int*)d_in[5];
    const int*   dst_mu  = (const int*)d_in[6];
    const float* w_mu    = (const float*)d_in[7];
    const float* c1_um_Wl = (const float*)d_in[8];
    const float* c1_um_Wr = (const float*)d_in[9];
    const float* c1_um_b  = (const float*)d_in[10];
    const float* c1_mu_Wl = (const float*)d_in[11];
    const float* c1_mu_Wr = (const float*)d_in[12];
    const float* c1_mu_b  = (const float*)d_in[13];
    const float* c2_um_Wl = (const float*)d_in[14];
    const float* c2_um_Wr = (const float*)d_in[15];
    const float* c2_um_b  = (const float*)d_in[16];
    const float* c2_mu_Wl = (const float*)d_in[17];
    const float* c2_mu_Wr = (const float*)d_in[18];
    const float* c2_mu_b  = (const float*)d_in[19];

    const int NU = in_sizes[0] / DFEAT;
    const int NM = in_sizes[1] / DFEAT;
    const int E_um = in_sizes[2];
    const int E_mu = in_sizes[5];

    char* p = (char*)d_ws;
    auto carve = [&](size_t bytes) { char* r = p; p += (bytes + 255) & ~(size_t)255; return r; };
    int* rowptr_m = (int*)carve((size_t)(NM + 1) * 4);
    int* rowptr_u = (int*)carve((size_t)(NU + 1) * 4);
    int* cursor_m = (int*)carve((size_t)NM * 4);
    int* cursor_u = (int*)carve((size_t)NU * 4);
    int* bsum_m   = (int*)carve(64 * 4);
    int* bsum_u   = (int*)carve(64 * 4);
    __bf16* xu_bf = (__bf16*)carve((size_t)NU * DFEAT * 2);
    __bf16* xm_bf = (__bf16*)carve((size_t)NM * DFEAT * 2);
    __bf16* ru_bf = (__bf16*)carve((size_t)NU * DFEAT * 2);
    __bf16* rm_bf = (__bf16*)carve((size_t)NM * DFEAT * 2);
    __bf16* wt_c1um = (__bf16*)carve(256 * 512 * 2);
    __bf16* wt_c1mu = (__bf16*)carve(256 * 512 * 2);
    __bf16* wt_c2um = (__bf16*)carve(256 * 512 * 2);
    __bf16* wt_c2mu = (__bf16*)carve(256 * 512 * 2);

    char* dtail = (char*)d_out + (size_t)(NU + NM) * DFEAT * 2;
    int*   rsrc_m = (int*)  (dtail);
    float* rw_m   = (float*)(dtail + (size_t)E_um * 4);
    int*   rsrc_u = (int*)  (dtail + (size_t)E_um * 8);
    float* rw_u   = (float*)(dtail + (size_t)E_um * 8 + (size_t)E_mu * 4);

    __bf16* mean1_u = (__bf16*)d_out;
    __bf16* mean1_m = (__bf16*)d_out + (size_t)NU * DFEAT;
    float* out_user  = (float*)d_out;
    float* out_movie = (float*)d_out + (size_t)NU * DFEAT;

    // ---- CSR build (merged launches) ----
    size_t msz = ((((size_t)(NM + 1) * 4) + 255) & ~(size_t)255) + (size_t)(NU + 1) * 4;
    hipMemsetAsync(rowptr_m, 0, msz, stream);   // covers rowptr_m + rowptr_u
    hist2_kernel<<<4096, 256, 0, stream>>>(dst_um, E_um, rowptr_m, dst_mu, E_mu, rowptr_u);
    const int nbM = (NM + 1 + 2047) / 2048;
    const int nbU = (NU + 1 + 2047) / 2048;
    scan_block2<<<nbM + nbU, 256, 0, stream>>>(rowptr_m, NM + 1, bsum_m, rowptr_u, NU + 1, bsum_u, nbM);
    scan_sums2<<<1, 128, 0, stream>>>(bsum_m, nbM, bsum_u, nbU);
    scan_add2<<<nbM + nbU, 256, 0, stream>>>(rowptr_m, NM + 1, bsum_m, rowptr_u, NU + 1, bsum_u, nbM);
    copy2_kernel<<<256, 256, 0, stream>>>(rowptr_m, cursor_m, NM, rowptr_u, cursor_u, NU);
    fill2_kernel<<<4096, 256, 0, stream>>>(dst_um, src_um, w_um, E_um, cursor_m, rsrc_m, rw_m,
                                           dst_mu, src_mu, w_mu, E_mu, cursor_u, rsrc_u, rw_u);

    // ---- bf16 features + packed fragment-major weights (merged) ----
    f32_to_bf16_2<<<2048, 256, 0, stream>>>(x_user, xu_bf, NU * DFEAT / 8,
                                            x_movie, xm_bf, NM * DFEAT / 8);
    WPack wp;
    wp.Wl[0] = c1_um_Wl; wp.Wr[0] = c1_um_Wr; wp.out[0] = wt_c1um;
    wp.Wl[1] = c1_mu_Wl; wp.Wr[1] = c1_mu_Wr; wp.out[1] = wt_c1mu;
    wp.Wl[2] = c2_um_Wl; wp.Wr[2] = c2_um_Wr; wp.out[2] = wt_c2um;
    wp.Wl[3] = c2_mu_Wl; wp.Wr[3] = c2_mu_Wr; wp.out[3] = wt_c2mu;
    wtrans4_kernel<<<2048, 256, 0, stream>>>(wp);

    // ---- layer 1 ----
    aggregate_bf16<<<(NM + 3) / 4, 256, 0, stream>>>(xu_bf, rsrc_m, rw_m, rowptr_m, mean1_m, NM);
    aggregate_bf16<<<(NU + 3) / 4, 256, 0, stream>>>(xm_bf, rsrc_u, rw_u, rowptr_u, mean1_u, NU);
    gemm_mfma<1><<<(NM + 63) / 64, 256, 0, stream>>>(mean1_m, xm_bf, wt_c1um, c1_um_b, xm_bf, rm_bf, NM);
    gemm_mfma<1><<<(NU + 63) / 64, 256, 0, stream>>>(mean1_u, xu_bf, wt_c1mu, c1_mu_b, xu_bf, ru_bf, NU);

    // ---- layer 2 ----
    __bf16* mean2_m = xm_bf;
    __bf16* mean2_u = xu_bf;
    aggregate_bf16<<<(NM + 3) / 4, 256, 0, stream>>>(ru_bf, rsrc_m, rw_m, rowptr_m, mean2_m, NM);
    aggregate_bf16<<<(NU + 3) / 4, 256, 0, stream>>>(rm_bf, rsrc_u, rw_u, rowptr_u, mean2_u, NU);
    gemm_mfma<0><<<(NM + 63) / 64, 256, 0, stream>>>(mean2_m, rm_bf, wt_c2um, c2_um_b, nullptr, out_movie, NM);
    gemm_mfma<0><<<(NU + 63) / 64, 256, 0, stream>>>(mean2_u, ru_bf, wt_c2mu, c2_mu_b, nullptr, out_user, NU);
}

// Round 13
// 686.663 us; speedup vs baseline: 1.3050x; 1.0100x over previous
//
#include <hip/hip_runtime.h>
#include <hip/hip_bf16.h>

#define DFEAT 256

typedef __bf16 bf16x8 __attribute__((ext_vector_type(8)));
typedef float  f32x4  __attribute__((ext_vector_type(4)));

// ---------------------------------------------------------------------------
// CSR build: histogram -> hierarchical scan (cursor written in scan_add)
// ---------------------------------------------------------------------------
__global__ void hist2_kernel(const int* __restrict__ dA, int nA, int* __restrict__ PA,
                             const int* __restrict__ dB, int nB, int* __restrict__ PB) {
    int half = gridDim.x >> 1;
    if (blockIdx.x < half) {
        for (int e = blockIdx.x * blockDim.x + threadIdx.x; e < nA; e += half * blockDim.x)
            atomicAdd(&PA[dA[e] + 1], 1);
    } else {
        for (int e = (blockIdx.x - half) * blockDim.x + threadIdx.x; e < nB; e += half * blockDim.x)
            atomicAdd(&PB[dB[e] + 1], 1);
    }
}

__global__ __launch_bounds__(256) void scan_block2(
    int* __restrict__ am, int nm, int* __restrict__ bsm,
    int* __restrict__ au, int nu, int* __restrict__ bsu, int nbM)
{
    __shared__ int wsum[4];
    int* a; int n; int* bsum; int bid;
    if ((int)blockIdx.x < nbM) { a = am; n = nm; bsum = bsm; bid = blockIdx.x; }
    else                       { a = au; n = nu; bsum = bsu; bid = blockIdx.x - nbM; }
    const int tid = threadIdx.x;
    const int lane = tid & 63, wv = tid >> 6;
    const int idx = bid * 2048 + tid * 8;
    int v[8];
    #pragma unroll
    for (int i = 0; i < 8; ++i) v[i] = (idx + i < n) ? a[idx + i] : 0;
    #pragma unroll
    for (int i = 1; i < 8; ++i) v[i] += v[i - 1];
    int tsum = v[7];
    int sc = tsum;
    #pragma unroll
    for (int off = 1; off < 64; off <<= 1) {
        int t = __shfl_up(sc, off);
        if (lane >= off) sc += t;
    }
    if (lane == 63) wsum[wv] = sc;
    __syncthreads();
    int wadd = 0;
    for (int w2 = 0; w2 < wv; ++w2) wadd += wsum[w2];
    int texcl = sc - tsum + wadd;
    #pragma unroll
    for (int i = 0; i < 8; ++i)
        if (idx + i < n) a[idx + i] = v[i] + texcl;
    if (tid == 255) bsum[bid] = sc + wadd;
}

__global__ void scan_sums2(int* __restrict__ bsm, int nbM, int* __restrict__ bsu, int nbU) {
    int wv = threadIdx.x >> 6;
    int lane = threadIdx.x & 63;
    int* bs = wv ? bsu : bsm;
    int nb  = wv ? nbU : nbM;
    int v = (lane < nb) ? bs[lane] : 0;
    #pragma unroll
    for (int off = 1; off < 64; off <<= 1) {
        int t = __shfl_up(v, off);
        if (lane >= off) v += t;
    }
    if (lane < nb) bs[lane] = v;
}

// adds block prefixes AND writes the cursor copy (cursor[d] = rowptr[d])
__global__ __launch_bounds__(256) void scan_add2(
    int* __restrict__ am, int nm, const int* __restrict__ bsm, int* __restrict__ curM,
    int* __restrict__ au, int nu, const int* __restrict__ bsu, int* __restrict__ curU, int nbM)
{
    int* a; int n; const int* bsum; int* cur; int bid;
    if ((int)blockIdx.x < nbM) { a = am; n = nm; bsum = bsm; cur = curM; bid = blockIdx.x; }
    else                       { a = au; n = nu; bsum = bsu; cur = curU; bid = blockIdx.x - nbM; }
    int add = (bid == 0) ? 0 : bsum[bid - 1];
    int idx = bid * 2048 + threadIdx.x * 8;
    #pragma unroll
    for (int i = 0; i < 8; ++i) {
        if (idx + i < n) {
            int v = a[idx + i] + add;
            if (bid > 0) a[idx + i] = v;
            if (idx + i < n - 1) cur[idx + i] = v;
        }
    }
}

// ---------------------------------------------------------------------------
// Mega-prep: [0,4096) edge fill (int2 records) | [4096,6144) f32->bf16 |
// [6144,8192) packed weight transpose. All independent.
// ---------------------------------------------------------------------------
struct PrepArgs {
    const int* dstA; const int* srcA; const float* wA; int nA;
    int* curA; int2* recA;
    const int* dstB; const int* srcB; const float* wB; int nB;
    int* curB; int2* recB;
    const float* xu; __bf16* xu_bf; int n8u;
    const float* xm; __bf16* xm_bf; int n8m;
    const float* Wl[4]; const float* Wr[4]; __bf16* wout[4];
};

__global__ __launch_bounds__(256) void mega_prep(PrepArgs p) {
    const int b = blockIdx.x;
    const int tid = threadIdx.x;
    if (b < 4096) {
        // fill: dst-sorted int2 records (one 8B store per edge)
        const int* dst; const int* src; const float* w; int n; int* cur; int2* rec;
        int lb;
        if (b < 2048) { dst = p.dstA; src = p.srcA; w = p.wA; n = p.nA; cur = p.curA; rec = p.recA; lb = b; }
        else          { dst = p.dstB; src = p.srcB; w = p.wB; n = p.nB; cur = p.curB; rec = p.recB; lb = b - 2048; }
        for (int e = lb * 256 + tid; e < n; e += 2048 * 256) {
            int pos = atomicAdd(&cur[dst[e]], 1);
            rec[pos] = make_int2(src[e], __float_as_int(w[e]));
        }
    } else if (b < 6144) {
        int total = p.n8u + p.n8m;
        for (int i = (b - 4096) * 256 + tid; i < total; i += 2048 * 256) {
            const float* in; __bf16* out; int j;
            if (i < p.n8u) { in = p.xu; out = p.xu_bf; j = i; }
            else           { in = p.xm; out = p.xm_bf; j = i - p.n8u; }
            float4 x = *reinterpret_cast<const float4*>(in + (size_t)j * 8);
            float4 y = *reinterpret_cast<const float4*>(in + (size_t)j * 8 + 4);
            bf16x8 v;
            v[0] = (__bf16)x.x; v[1] = (__bf16)x.y; v[2] = (__bf16)x.z; v[3] = (__bf16)x.w;
            v[4] = (__bf16)y.x; v[5] = (__bf16)y.y; v[6] = (__bf16)y.z; v[7] = (__bf16)y.w;
            *reinterpret_cast<bf16x8*>(out + (size_t)j * 8) = v;
        }
    } else {
        // packed fragment-major weights: frag f = ncg*16+kc; lane l bytes f*1024+l*16
        int t = (b - 6144) * 256 + tid;          // 0 .. 524287
        int set = t >> 17;
        int e2  = t & 131071;
        int f = e2 >> 9;
        int e = e2 & 511;
        int l = e >> 3;
        int j = e & 7;
        int ncg = f >> 4;
        int kc  = f & 15;
        int col = ncg * 16 + (l & 15);
        int k   = kc * 32 + (l >> 4) * 8 + j;
        float v = (k < 256) ? p.Wl[set][(size_t)k * 256 + col]
                            : p.Wr[set][(size_t)(k - 256) * 256 + col];
        p.wout[set][e2] = (__bf16)v;
    }
}

// ---------------------------------------------------------------------------
// Dual aggregation (movie side blocks [0,nbA), user side rest): one wave per
// dst row; 2 edges per wave-step (32 lanes x 16B), 16 edges in flight;
// cross-half combine via shfl_xor(32). Records are int2 (src, w-bits).
// ---------------------------------------------------------------------------
__global__ __launch_bounds__(256) void agg_dual(
    const __bf16* __restrict__ xA, const int2* __restrict__ recA,
    const int* __restrict__ rpA, __bf16* __restrict__ meanA, int ndA, int nbA,
    const __bf16* __restrict__ xB, const int2* __restrict__ recB,
    const int* __restrict__ rpB, __bf16* __restrict__ meanB, int ndB)
{
    const __bf16* xsrc; const int2* rec; const int* rowptr; __bf16* mean; int ndst; int lb;
    if ((int)blockIdx.x < nbA) { xsrc = xA; rec = recA; rowptr = rpA; mean = meanA; ndst = ndA; lb = blockIdx.x; }
    else                       { xsrc = xB; rec = recB; rowptr = rpB; mean = meanB; ndst = ndB; lb = blockIdx.x - nbA; }
    int wid  = lb * 4 + (threadIdx.x >> 6);
    int lane = threadIdx.x & 63;
    if (wid >= ndst) return;
    int beg = rowptr[wid], end = rowptr[wid + 1];
    const int half = lane >> 5, hl = lane & 31;
    const __bf16* xcol = xsrc + hl * 8;
    float acc[8];
    #pragma unroll
    for (int i = 0; i < 8; ++i) acc[i] = 0.f;

    int j0 = beg;
    while (j0 < end) {
        int m = end - j0; if (m > 64) m = 64;
        int2 rl = (lane < m) ? rec[j0 + lane] : make_int2(0, 0);
        int   sl = rl.x;
        int   wl = rl.y;
        int t = 0;
        for (; t + 16 <= m; t += 16) {
            bf16x8 v[8]; float wt[8];
            #pragma unroll
            for (int u = 0; u < 8; ++u) {
                int tt = t + u * 2;
                int e0 = __builtin_amdgcn_readlane(sl, tt);
                int e1 = __builtin_amdgcn_readlane(sl, tt + 1);
                int w0 = __builtin_amdgcn_readlane(wl, tt);
                int w1 = __builtin_amdgcn_readlane(wl, tt + 1);
                int s = half ? e1 : e0;
                wt[u] = __int_as_float(half ? w1 : w0);
                v[u] = *reinterpret_cast<const bf16x8*>(xcol + (size_t)s * DFEAT);
            }
            #pragma unroll
            for (int u = 0; u < 8; ++u)
                #pragma unroll
                for (int i = 0; i < 8; ++i) acc[i] += wt[u] * (float)v[u][i];
        }
        for (; t < m; t += 2) {
            int e0 = __builtin_amdgcn_readlane(sl, t);
            int e1 = __builtin_amdgcn_readlane(sl, (t + 1 < 64) ? t + 1 : 63);
            int w0 = __builtin_amdgcn_readlane(wl, t);
            int w1 = __builtin_amdgcn_readlane(wl, (t + 1 < 64) ? t + 1 : 63);
            int s = half ? e1 : e0;
            float wv2 = __int_as_float(half ? w1 : w0);
            if (half && t + 1 >= m) wv2 = 0.f;
            bf16x8 v = *reinterpret_cast<const bf16x8*>(xcol + (size_t)s * DFEAT);
            #pragma unroll
            for (int i = 0; i < 8; ++i) acc[i] += wv2 * (float)v[i];
        }
        j0 += m;
    }

    #pragma unroll
    for (int i = 0; i < 8; ++i) acc[i] += __shfl_xor(acc[i], 32);
    float inv = (end > beg) ? 1.0f / (float)(end - beg) : 0.0f;
    if (half == 0) {
        bf16x8 o;
        #pragma unroll
        for (int i = 0; i < 8; ++i) o[i] = (__bf16)(acc[i] * inv);
        *reinterpret_cast<bf16x8*>(mean + (size_t)wid * DFEAT + hl * 8) = o;
    }
}

// ---------------------------------------------------------------------------
// Dual MFMA GEMM, 2-deep pipeline (R10 structure): out = epi(A@Wl + B@Wr + b)
// Side selected by block range. 256 thr = 4 waves; wave w owns cols
// [w*64,+64); BM=64. K=512 = 8 chunks of 64 (0-3 read A, 4-7 read B).
//  - A: 3 LDS buffers, stage(c+2) issued in iter c (2 iters of cover).
//  - B: packed WTP, double-buffered in registers, loadB(c+1) in iter c.
//  - vmcnt(10) before each barrier: completes stage(c)+older, keeps
//    stage(c+2)+B(c+1) (2+8 loads) in flight.
// ---------------------------------------------------------------------------
struct GemmSide {
    const __bf16* A; const __bf16* B; const __bf16* W;
    const float* bias; const __bf16* resid; void* out; int n;
};

template<int EPI>
__global__ __launch_bounds__(256) void gemm_dual(GemmSide s0, GemmSide s1, int nb0) {
    __shared__ char sA[3][64 * 128];      // 3 x 8 KB

    const GemmSide& S = ((int)blockIdx.x < nb0) ? s0 : s1;
    const int lblk = ((int)blockIdx.x < nb0) ? blockIdx.x : blockIdx.x - nb0;
    const __bf16* __restrict__ Amat = S.A;
    const __bf16* __restrict__ Bmat = S.B;
    const char* Wb = reinterpret_cast<const char*>(S.W);
    const int n = S.n;

    const int tid  = threadIdx.x;
    const int lane = tid & 63;
    const int wv   = tid >> 6;
    const int lo   = lane & 15;
    const int hi   = lane >> 4;
    const int brow = lblk * 64;
    const int wcol = wv * 64;
    const int nm1  = n - 1;

    f32x4 acc[4][4];
    #pragma unroll
    for (int i = 0; i < 4; ++i)
        #pragma unroll
        for (int j = 0; j < 4; ++j) acc[i][j] = (f32x4){0.f, 0.f, 0.f, 0.f};

    auto stage = [&](int chunk, int buf) {
        const __bf16* mat = (chunk < 4) ? Amat : Bmat;
        const int kbyte = (chunk & 3) * 128;
        #pragma unroll
        for (int q = 0; q < 2; ++q) {
            int s = q * 256 + tid;
            int r = s >> 3, sub = s & 7;
            int grow = brow + r; if (grow > nm1) grow = nm1;
            int srcoff = (sub * 16) ^ ((r & 7) << 4);
            const char* g = reinterpret_cast<const char*>(mat) + (size_t)grow * 512 + kbyte + srcoff;
            __builtin_amdgcn_global_load_lds(
                (const __attribute__((address_space(1))) void*)g,
                (__attribute__((address_space(3))) void*)(sA[buf] + s * 16), 16, 0, 0);
        }
    };

    const int lb = lane * 16;
    bf16x8 bqA[2][4], bqB[2][4];
    auto loadB = [&](int chunk, bf16x8 (&dst)[2][4]) {
        #pragma unroll
        for (int ks = 0; ks < 2; ++ks)
            #pragma unroll
            for (int nn = 0; nn < 4; ++nn)
                dst[ks][nn] = *reinterpret_cast<const bf16x8*>(
                    Wb + (size_t)(((wv * 4 + nn) * 16 + chunk * 2 + ks) << 10) + lb);
    };

    stage(0, 0);
    stage(1, 1);
    loadB(0, bqA);

    #pragma unroll
    for (int c = 0; c < 8; ++c) {
        asm volatile("s_waitcnt vmcnt(10)" ::: "memory");
        __builtin_amdgcn_s_barrier();
        __builtin_amdgcn_sched_barrier(0);
        if (c < 6) stage(c + 2, (c + 2) % 3);
        const int cur = c % 3;
        auto compute = [&](bf16x8 (&bq)[2][4]) {
            #pragma unroll
            for (int ks = 0; ks < 2; ++ks) {
                const int kb = ks * 64 + hi * 16;
                #pragma unroll
                for (int mm = 0; mm < 4; ++mm) {
                    int r = mm * 16 + lo;
                    bf16x8 a = *reinterpret_cast<const bf16x8*>(
                        sA[cur] + r * 128 + (kb ^ ((r & 7) << 4)));
                    #pragma unroll
                    for (int nn = 0; nn < 4; ++nn)
                        acc[mm][nn] = __builtin_amdgcn_mfma_f32_16x16x32_bf16(
                            a, bq[ks][nn], acc[mm][nn], 0, 0, 0);
                }
            }
        };
        if ((c & 1) == 0) { if (c < 7) loadB(c + 1, bqB); compute(bqA); }
        else              { if (c < 7) loadB(c + 1, bqA); compute(bqB); }
    }

    #pragma unroll
    for (int mm = 0; mm < 4; ++mm) {
        #pragma unroll
        for (int nn = 0; nn < 4; ++nn) {
            int col = wcol + nn * 16 + lo;
            float bv2 = S.bias[col];
            #pragma unroll
            for (int r = 0; r < 4; ++r) {
                int grow = brow + mm * 16 + hi * 4 + r;
                if (grow >= n) continue;
                float v = acc[mm][nn][r] + bv2;
                if (EPI == 1) {
                    float rv = (float)S.resid[(size_t)grow * DFEAT + col];
                    ((__bf16*)S.out)[(size_t)grow * DFEAT + col] =
                        (__bf16)(rv + fmaxf(v, 0.f));
                } else {
                    ((float*)S.out)[(size_t)grow * DFEAT + col] = v;
                }
            }
        }
    }
}

// ---------------------------------------------------------------------------
extern "C" void kernel_launch(void* const* d_in, const int* in_sizes, int n_in,
                              void* d_out, int out_size, void* d_ws, size_t ws_size,
                              hipStream_t stream) {
    const float* x_user  = (const float*)d_in[0];
    const float* x_movie = (const float*)d_in[1];
    const int*   src_um  = (const int*)d_in[2];
    const int*   dst_um  = (const int*)d_in[3];
    const float* w_um    = (const float*)d_in[4];
    const int*   src_mu  = (const int*)d_in[5];
    const int*   dst_mu  = (const int*)d_in[6];
    const float* w_mu    = (const float*)d_in[7];
    const float* c1_um_Wl = (const float*)d_in[8];
    const float* c1_um_Wr = (const float*)d_in[9];
    const float* c1_um_b  = (const float*)d_in[10];
    const float* c1_mu_Wl = (const float*)d_in[11];
    const float* c1_mu_Wr = (const float*)d_in[12];
    const float* c1_mu_b  = (const float*)d_in[13];
    const float* c2_um_Wl = (const float*)d_in[14];
    const float* c2_um_Wr = (const float*)d_in[15];
    const float* c2_um_b  = (const float*)d_in[16];
    const float* c2_mu_Wl = (const float*)d_in[17];
    const float* c2_mu_Wr = (const float*)d_in[18];
    const float* c2_mu_b  = (const float*)d_in[19];

    const int NU = in_sizes[0] / DFEAT;
    const int NM = in_sizes[1] / DFEAT;
    const int E_um = in_sizes[2];
    const int E_mu = in_sizes[5];

    char* p = (char*)d_ws;
    auto carve = [&](size_t bytes) { char* r = p; p += (bytes + 255) & ~(size_t)255; return r; };
    int* rowptr_m = (int*)carve((size_t)(NM + 1) * 4);
    int* rowptr_u = (int*)carve((size_t)(NU + 1) * 4);
    int* cursor_m = (int*)carve((size_t)NM * 4);
    int* cursor_u = (int*)carve((size_t)NU * 4);
    int* bsum_m   = (int*)carve(64 * 4);
    int* bsum_u   = (int*)carve(64 * 4);
    __bf16* xu_bf = (__bf16*)carve((size_t)NU * DFEAT * 2);
    __bf16* xm_bf = (__bf16*)carve((size_t)NM * DFEAT * 2);
    __bf16* ru_bf = (__bf16*)carve((size_t)NU * DFEAT * 2);
    __bf16* rm_bf = (__bf16*)carve((size_t)NM * DFEAT * 2);
    __bf16* wt_c1um = (__bf16*)carve(256 * 512 * 2);
    __bf16* wt_c1mu = (__bf16*)carve(256 * 512 * 2);
    __bf16* wt_c2um = (__bf16*)carve(256 * 512 * 2);
    __bf16* wt_c2mu = (__bf16*)carve(256 * 512 * 2);

    // int2 records in the dead tail of d_out (consumed before final writes)
    char* dtail = (char*)d_out + (size_t)(NU + NM) * DFEAT * 2;
    int2* rec_m = (int2*)(dtail);
    int2* rec_u = (int2*)(dtail + (size_t)E_um * 8);

    __bf16* mean1_u = (__bf16*)d_out;
    __bf16* mean1_m = (__bf16*)d_out + (size_t)NU * DFEAT;
    float* out_user  = (float*)d_out;
    float* out_movie = (float*)d_out + (size_t)NU * DFEAT;

    // ---- CSR build ----
    size_t msz = ((((size_t)(NM + 1) * 4) + 255) & ~(size_t)255) + (size_t)(NU + 1) * 4;
    hipMemsetAsync(rowptr_m, 0, msz, stream);   // covers rowptr_m + rowptr_u
    hist2_kernel<<<4096, 256, 0, stream>>>(dst_um, E_um, rowptr_m, dst_mu, E_mu, rowptr_u);
    const int nbM = (NM + 1 + 2047) / 2048;
    const int nbU = (NU + 1 + 2047) / 2048;
    scan_block2<<<nbM + nbU, 256, 0, stream>>>(rowptr_m, NM + 1, bsum_m, rowptr_u, NU + 1, bsum_u, nbM);
    scan_sums2<<<1, 128, 0, stream>>>(bsum_m, nbM, bsum_u, nbU);
    scan_add2<<<nbM + nbU, 256, 0, stream>>>(rowptr_m, NM + 1, bsum_m, cursor_m,
                                             rowptr_u, NU + 1, bsum_u, cursor_u, nbM);

    // ---- mega prep: fill records + bf16 features + packed weights ----
    PrepArgs pa;
    pa.dstA = dst_um; pa.srcA = src_um; pa.wA = w_um; pa.nA = E_um; pa.curA = cursor_m; pa.recA = rec_m;
    pa.dstB = dst_mu; pa.srcB = src_mu; pa.wB = w_mu; pa.nB = E_mu; pa.curB = cursor_u; pa.recB = rec_u;
    pa.xu = x_user;  pa.xu_bf = xu_bf; pa.n8u = NU * DFEAT / 8;
    pa.xm = x_movie; pa.xm_bf = xm_bf; pa.n8m = NM * DFEAT / 8;
    pa.Wl[0] = c1_um_Wl; pa.Wr[0] = c1_um_Wr; pa.wout[0] = wt_c1um;
    pa.Wl[1] = c1_mu_Wl; pa.Wr[1] = c1_mu_Wr; pa.wout[1] = wt_c1mu;
    pa.Wl[2] = c2_um_Wl; pa.Wr[2] = c2_um_Wr; pa.wout[2] = wt_c2um;
    pa.Wl[3] = c2_mu_Wl; pa.Wr[3] = c2_mu_Wr; pa.wout[3] = wt_c2mu;
    mega_prep<<<8192, 256, 0, stream>>>(pa);

    const int gaM = (NM + 3) / 4, gaU = (NU + 3) / 4;
    const int gbM = (NM + 63) / 64, gbU = (NU + 63) / 64;

    // ---- layer 1 ----
    agg_dual<<<gaM + gaU, 256, 0, stream>>>(xu_bf, rec_m, rowptr_m, mean1_m, NM, gaM,
                                            xm_bf, rec_u, rowptr_u, mean1_u, NU);
    GemmSide g1m = {mean1_m, xm_bf, wt_c1um, c1_um_b, xm_bf, rm_bf, NM};
    GemmSide g1u = {mean1_u, xu_bf, wt_c1mu, c1_mu_b, xu_bf, ru_bf, NU};
    gemm_dual<1><<<gbM + gbU, 256, 0, stream>>>(g1m, g1u, gbM);

    // ---- layer 2 (means reuse dead x_bf buffers) ----
    __bf16* mean2_m = xm_bf;
    __bf16* mean2_u = xu_bf;
    agg_dual<<<gaM + gaU, 256, 0, stream>>>(ru_bf, rec_m, rowptr_m, mean2_m, NM, gaM,
                                            rm_bf, rec_u, rowptr_u, mean2_u, NU);
    GemmSide g2m = {mean2_m, rm_bf, wt_c2um, c2_um_b, nullptr, out_movie, NM};
    GemmSide g2u = {mean2_u, ru_bf, wt_c2mu, c2_mu_b, nullptr, out_user, NU};
    gemm_dual<0><<<gbM + gbU, 256, 0, stream>>>(g2m, g2u, gbM);
}

// Round 14
// 621.679 us; speedup vs baseline: 1.4414x; 1.1045x over previous
//
#include <hip/hip_runtime.h>
#include <hip/hip_bf16.h>

#define DFEAT 256

typedef __bf16 bf16x8 __attribute__((ext_vector_type(8)));
typedef float  f32x4  __attribute__((ext_vector_type(4)));

// ---------------------------------------------------------------------------
// CSR build: histogram -> hierarchical scan (cursor written in scan_add)
// ---------------------------------------------------------------------------
__global__ void hist2_kernel(const int* __restrict__ dA, int nA, int* __restrict__ PA,
                             const int* __restrict__ dB, int nB, int* __restrict__ PB) {
    int half = gridDim.x >> 1;
    if (blockIdx.x < half) {
        for (int e = blockIdx.x * blockDim.x + threadIdx.x; e < nA; e += half * blockDim.x)
            atomicAdd(&PA[dA[e] + 1], 1);
    } else {
        for (int e = (blockIdx.x - half) * blockDim.x + threadIdx.x; e < nB; e += half * blockDim.x)
            atomicAdd(&PB[dB[e] + 1], 1);
    }
}

__global__ __launch_bounds__(256) void scan_block2(
    int* __restrict__ am, int nm, int* __restrict__ bsm,
    int* __restrict__ au, int nu, int* __restrict__ bsu, int nbM)
{
    __shared__ int wsum[4];
    int* a; int n; int* bsum; int bid;
    if ((int)blockIdx.x < nbM) { a = am; n = nm; bsum = bsm; bid = blockIdx.x; }
    else                       { a = au; n = nu; bsum = bsu; bid = blockIdx.x - nbM; }
    const int tid = threadIdx.x;
    const int lane = tid & 63, wv = tid >> 6;
    const int idx = bid * 2048 + tid * 8;
    int v[8];
    #pragma unroll
    for (int i = 0; i < 8; ++i) v[i] = (idx + i < n) ? a[idx + i] : 0;
    #pragma unroll
    for (int i = 1; i < 8; ++i) v[i] += v[i - 1];
    int tsum = v[7];
    int sc = tsum;
    #pragma unroll
    for (int off = 1; off < 64; off <<= 1) {
        int t = __shfl_up(sc, off);
        if (lane >= off) sc += t;
    }
    if (lane == 63) wsum[wv] = sc;
    __syncthreads();
    int wadd = 0;
    for (int w2 = 0; w2 < wv; ++w2) wadd += wsum[w2];
    int texcl = sc - tsum + wadd;
    #pragma unroll
    for (int i = 0; i < 8; ++i)
        if (idx + i < n) a[idx + i] = v[i] + texcl;
    if (tid == 255) bsum[bid] = sc + wadd;
}

__global__ void scan_sums2(int* __restrict__ bsm, int nbM, int* __restrict__ bsu, int nbU) {
    int wv = threadIdx.x >> 6;
    int lane = threadIdx.x & 63;
    int* bs = wv ? bsu : bsm;
    int nb  = wv ? nbU : nbM;
    int v = (lane < nb) ? bs[lane] : 0;
    #pragma unroll
    for (int off = 1; off < 64; off <<= 1) {
        int t = __shfl_up(v, off);
        if (lane >= off) v += t;
    }
    if (lane < nb) bs[lane] = v;
}

// adds block prefixes AND writes the cursor copy (cursor[d] = rowptr[d])
__global__ __launch_bounds__(256) void scan_add2(
    int* __restrict__ am, int nm, const int* __restrict__ bsm, int* __restrict__ curM,
    int* __restrict__ au, int nu, const int* __restrict__ bsu, int* __restrict__ curU, int nbM)
{
    int* a; int n; const int* bsum; int* cur; int bid;
    if ((int)blockIdx.x < nbM) { a = am; n = nm; bsum = bsm; cur = curM; bid = blockIdx.x; }
    else                       { a = au; n = nu; bsum = bsu; cur = curU; bid = blockIdx.x - nbM; }
    int add = (bid == 0) ? 0 : bsum[bid - 1];
    int idx = bid * 2048 + threadIdx.x * 8;
    #pragma unroll
    for (int i = 0; i < 8; ++i) {
        if (idx + i < n) {
            int v = a[idx + i] + add;
            if (bid > 0) a[idx + i] = v;
            if (idx + i < n - 1) cur[idx + i] = v;
        }
    }
}

// ---------------------------------------------------------------------------
// Mega-prep: [0,4096) XCD-partitioned edge fill | [4096,6144) f32->bf16 |
// [6144,8192) packed weight transpose. All independent.
// Fill partition: dsts split into 8 ranges; only blocks with within&7 == r
// (HW round-robin puts them on one XCD) write range r's records -> each
// record line accumulates in a single XCD's L2, one writeback per line.
// Edge stream scanned 8x (L3-resident after first pass).
// ---------------------------------------------------------------------------
struct PrepArgs {
    const int* dstA; const int* srcA; const float* wA; int nA; int ndA;
    int* curA; int2* recA;
    const int* dstB; const int* srcB; const float* wB; int nB; int ndB;
    int* curB; int2* recB;
    const float* xu; __bf16* xu_bf; int n8u;
    const float* xm; __bf16* xm_bf; int n8m;
    const float* Wl[4]; const float* Wr[4]; __bf16* wout[4];
};

__global__ __launch_bounds__(256) void mega_prep(PrepArgs p) {
    const int b = blockIdx.x;
    const int tid = threadIdx.x;
    if (b < 4096) {
        const int* dst; const int* src; const float* w; int n; int ndst; int* cur; int2* rec;
        int within;
        if (b < 2048) { dst = p.dstA; src = p.srcA; w = p.wA; n = p.nA; ndst = p.ndA; cur = p.curA; rec = p.recA; within = b; }
        else          { dst = p.dstB; src = p.srcB; w = p.wB; n = p.nB; ndst = p.ndB; cur = p.curB; rec = p.recB; within = b - 2048; }
        const int r  = within & 7;          // dst-range == XCD group (blockIdx%8)
        const int lb = within >> 3;         // 0..255 within range-group
        const int rsz = (ndst + 7) >> 3;
        const int d0 = r * rsz;
        const int d1 = (d0 + rsz < ndst) ? d0 + rsz : ndst;
        for (int e = lb * 256 + tid; e < n; e += 256 * 256) {
            int d = dst[e];                 // coalesced; L3-hot after pass 1
            if (d >= d0 && d < d1) {
                int pos = atomicAdd(&cur[d], 1);
                rec[pos] = make_int2(src[e], __float_as_int(w[e]));
            }
        }
    } else if (b < 6144) {
        int total = p.n8u + p.n8m;
        for (int i = (b - 4096) * 256 + tid; i < total; i += 2048 * 256) {
            const float* in; __bf16* out; int j;
            if (i < p.n8u) { in = p.xu; out = p.xu_bf; j = i; }
            else           { in = p.xm; out = p.xm_bf; j = i - p.n8u; }
            float4 x = *reinterpret_cast<const float4*>(in + (size_t)j * 8);
            float4 y = *reinterpret_cast<const float4*>(in + (size_t)j * 8 + 4);
            bf16x8 v;
            v[0] = (__bf16)x.x; v[1] = (__bf16)x.y; v[2] = (__bf16)x.z; v[3] = (__bf16)x.w;
            v[4] = (__bf16)y.x; v[5] = (__bf16)y.y; v[6] = (__bf16)y.z; v[7] = (__bf16)y.w;
            *reinterpret_cast<bf16x8*>(out + (size_t)j * 8) = v;
        }
    } else {
        // packed fragment-major weights: frag f = ncg*16+kc; lane l bytes f*1024+l*16
        int t = (b - 6144) * 256 + tid;          // 0 .. 524287
        int set = t >> 17;
        int e2  = t & 131071;
        int f = e2 >> 9;
        int e = e2 & 511;
        int l = e >> 3;
        int j = e & 7;
        int ncg = f >> 4;
        int kc  = f & 15;
        int col = ncg * 16 + (l & 15);
        int k   = kc * 32 + (l >> 4) * 8 + j;
        float v = (k < 256) ? p.Wl[set][(size_t)k * 256 + col]
                            : p.Wr[set][(size_t)(k - 256) * 256 + col];
        p.wout[set][e2] = (__bf16)v;
    }
}

// ---------------------------------------------------------------------------
// Dual aggregation (movie side blocks [0,nbA), user side rest): one wave per
// dst row; 2 edges per wave-step (32 lanes x 16B), 16 edges in flight;
// cross-half combine via shfl_xor(32). Records are int2 (src, w-bits).
// ---------------------------------------------------------------------------
__global__ __launch_bounds__(256) void agg_dual(
    const __bf16* __restrict__ xA, const int2* __restrict__ recA,
    const int* __restrict__ rpA, __bf16* __restrict__ meanA, int ndA, int nbA,
    const __bf16* __restrict__ xB, const int2* __restrict__ recB,
    const int* __restrict__ rpB, __bf16* __restrict__ meanB, int ndB)
{
    const __bf16* xsrc; const int2* rec; const int* rowptr; __bf16* mean; int ndst; int lb;
    if ((int)blockIdx.x < nbA) { xsrc = xA; rec = recA; rowptr = rpA; mean = meanA; ndst = ndA; lb = blockIdx.x; }
    else                       { xsrc = xB; rec = recB; rowptr = rpB; mean = meanB; ndst = ndB; lb = blockIdx.x - nbA; }
    int wid  = lb * 4 + (threadIdx.x >> 6);
    int lane = threadIdx.x & 63;
    if (wid >= ndst) return;
    int beg = rowptr[wid], end = rowptr[wid + 1];
    const int half = lane >> 5, hl = lane & 31;
    const __bf16* xcol = xsrc + hl * 8;
    float acc[8];
    #pragma unroll
    for (int i = 0; i < 8; ++i) acc[i] = 0.f;

    int j0 = beg;
    while (j0 < end) {
        int m = end - j0; if (m > 64) m = 64;
        int2 rl = (lane < m) ? rec[j0 + lane] : make_int2(0, 0);
        int   sl = rl.x;
        int   wl = rl.y;
        int t = 0;
        for (; t + 16 <= m; t += 16) {
            bf16x8 v[8]; float wt[8];
            #pragma unroll
            for (int u = 0; u < 8; ++u) {
                int tt = t + u * 2;
                int e0 = __builtin_amdgcn_readlane(sl, tt);
                int e1 = __builtin_amdgcn_readlane(sl, tt + 1);
                int w0 = __builtin_amdgcn_readlane(wl, tt);
                int w1 = __builtin_amdgcn_readlane(wl, tt + 1);
                int s = half ? e1 : e0;
                wt[u] = __int_as_float(half ? w1 : w0);
                v[u] = *reinterpret_cast<const bf16x8*>(xcol + (size_t)s * DFEAT);
            }
            #pragma unroll
            for (int u = 0; u < 8; ++u)
                #pragma unroll
                for (int i = 0; i < 8; ++i) acc[i] += wt[u] * (float)v[u][i];
        }
        for (; t < m; t += 2) {
            int e0 = __builtin_amdgcn_readlane(sl, t);
            int e1 = __builtin_amdgcn_readlane(sl, (t + 1 < 64) ? t + 1 : 63);
            int w0 = __builtin_amdgcn_readlane(wl, t);
            int w1 = __builtin_amdgcn_readlane(wl, (t + 1 < 64) ? t + 1 : 63);
            int s = half ? e1 : e0;
            float wv2 = __int_as_float(half ? w1 : w0);
            if (half && t + 1 >= m) wv2 = 0.f;
            bf16x8 v = *reinterpret_cast<const bf16x8*>(xcol + (size_t)s * DFEAT);
            #pragma unroll
            for (int i = 0; i < 8; ++i) acc[i] += wv2 * (float)v[i];
        }
        j0 += m;
    }

    #pragma unroll
    for (int i = 0; i < 8; ++i) acc[i] += __shfl_xor(acc[i], 32);
    float inv = (end > beg) ? 1.0f / (float)(end - beg) : 0.0f;
    if (half == 0) {
        bf16x8 o;
        #pragma unroll
        for (int i = 0; i < 8; ++i) o[i] = (__bf16)(acc[i] * inv);
        *reinterpret_cast<bf16x8*>(mean + (size_t)wid * DFEAT + hl * 8) = o;
    }
}

// ---------------------------------------------------------------------------
// Dual MFMA GEMM, 2-deep pipeline (R10 structure): out = epi(A@Wl + B@Wr + b)
// ---------------------------------------------------------------------------
struct GemmSide {
    const __bf16* A; const __bf16* B; const __bf16* W;
    const float* bias; const __bf16* resid; void* out; int n;
};

template<int EPI>
__global__ __launch_bounds__(256) void gemm_dual(GemmSide s0, GemmSide s1, int nb0) {
    __shared__ char sA[3][64 * 128];      // 3 x 8 KB

    const GemmSide& S = ((int)blockIdx.x < nb0) ? s0 : s1;
    const int lblk = ((int)blockIdx.x < nb0) ? blockIdx.x : blockIdx.x - nb0;
    const __bf16* __restrict__ Amat = S.A;
    const __bf16* __restrict__ Bmat = S.B;
    const char* Wb = reinterpret_cast<const char*>(S.W);
    const int n = S.n;

    const int tid  = threadIdx.x;
    const int lane = tid & 63;
    const int wv   = tid >> 6;
    const int lo   = lane & 15;
    const int hi   = lane >> 4;
    const int brow = lblk * 64;
    const int wcol = wv * 64;
    const int nm1  = n - 1;

    f32x4 acc[4][4];
    #pragma unroll
    for (int i = 0; i < 4; ++i)
        #pragma unroll
        for (int j = 0; j < 4; ++j) acc[i][j] = (f32x4){0.f, 0.f, 0.f, 0.f};

    auto stage = [&](int chunk, int buf) {
        const __bf16* mat = (chunk < 4) ? Amat : Bmat;
        const int kbyte = (chunk & 3) * 128;
        #pragma unroll
        for (int q = 0; q < 2; ++q) {
            int s = q * 256 + tid;
            int r = s >> 3, sub = s & 7;
            int grow = brow + r; if (grow > nm1) grow = nm1;
            int srcoff = (sub * 16) ^ ((r & 7) << 4);
            const char* g = reinterpret_cast<const char*>(mat) + (size_t)grow * 512 + kbyte + srcoff;
            __builtin_amdgcn_global_load_lds(
                (const __attribute__((address_space(1))) void*)g,
                (__attribute__((address_space(3))) void*)(sA[buf] + s * 16), 16, 0, 0);
        }
    };

    const int lb = lane * 16;
    bf16x8 bqA[2][4], bqB[2][4];
    auto loadB = [&](int chunk, bf16x8 (&dst)[2][4]) {
        #pragma unroll
        for (int ks = 0; ks < 2; ++ks)
            #pragma unroll
            for (int nn = 0; nn < 4; ++nn)
                dst[ks][nn] = *reinterpret_cast<const bf16x8*>(
                    Wb + (size_t)(((wv * 4 + nn) * 16 + chunk * 2 + ks) << 10) + lb);
    };

    stage(0, 0);
    stage(1, 1);
    loadB(0, bqA);

    #pragma unroll
    for (int c = 0; c < 8; ++c) {
        asm volatile("s_waitcnt vmcnt(10)" ::: "memory");
        __builtin_amdgcn_s_barrier();
        __builtin_amdgcn_sched_barrier(0);
        if (c < 6) stage(c + 2, (c + 2) % 3);
        const int cur = c % 3;
        auto compute = [&](bf16x8 (&bq)[2][4]) {
            #pragma unroll
            for (int ks = 0; ks < 2; ++ks) {
                const int kb = ks * 64 + hi * 16;
                #pragma unroll
                for (int mm = 0; mm < 4; ++mm) {
                    int r = mm * 16 + lo;
                    bf16x8 a = *reinterpret_cast<const bf16x8*>(
                        sA[cur] + r * 128 + (kb ^ ((r & 7) << 4)));
                    #pragma unroll
                    for (int nn = 0; nn < 4; ++nn)
                        acc[mm][nn] = __builtin_amdgcn_mfma_f32_16x16x32_bf16(
                            a, bq[ks][nn], acc[mm][nn], 0, 0, 0);
                }
            }
        };
        if ((c & 1) == 0) { if (c < 7) loadB(c + 1, bqB); compute(bqA); }
        else              { if (c < 7) loadB(c + 1, bqA); compute(bqB); }
    }

    #pragma unroll
    for (int mm = 0; mm < 4; ++mm) {
        #pragma unroll
        for (int nn = 0; nn < 4; ++nn) {
            int col = wcol + nn * 16 + lo;
            float bv2 = S.bias[col];
            #pragma unroll
            for (int r = 0; r < 4; ++r) {
                int grow = brow + mm * 16 + hi * 4 + r;
                if (grow >= n) continue;
                float v = acc[mm][nn][r] + bv2;
                if (EPI == 1) {
                    float rv = (float)S.resid[(size_t)grow * DFEAT + col];
                    ((__bf16*)S.out)[(size_t)grow * DFEAT + col] =
                        (__bf16)(rv + fmaxf(v, 0.f));
                } else {
                    ((float*)S.out)[(size_t)grow * DFEAT + col] = v;
                }
            }
        }
    }
}

// ---------------------------------------------------------------------------
extern "C" void kernel_launch(void* const* d_in, const int* in_sizes, int n_in,
                              void* d_out, int out_size, void* d_ws, size_t ws_size,
                              hipStream_t stream) {
    const float* x_user  = (const float*)d_in[0];
    const float* x_movie = (const float*)d_in[1];
    const int*   src_um  = (const int*)d_in[2];
    const int*   dst_um  = (const int*)d_in[3];
    const float* w_um    = (const float*)d_in[4];
    const int*   src_mu  = (const int*)d_in[5];
    const int*   dst_mu  = (const int*)d_in[6];
    const float* w_mu    = (const float*)d_in[7];
    const float* c1_um_Wl = (const float*)d_in[8];
    const float* c1_um_Wr = (const float*)d_in[9];
    const float* c1_um_b  = (const float*)d_in[10];
    const float* c1_mu_Wl = (const float*)d_in[11];
    const float* c1_mu_Wr = (const float*)d_in[12];
    const float* c1_mu_b  = (const float*)d_in[13];
    const float* c2_um_Wl = (const float*)d_in[14];
    const float* c2_um_Wr = (const float*)d_in[15];
    const float* c2_um_b  = (const float*)d_in[16];
    const float* c2_mu_Wl = (const float*)d_in[17];
    const float* c2_mu_Wr = (const float*)d_in[18];
    const float* c2_mu_b  = (const float*)d_in[19];

    const int NU = in_sizes[0] / DFEAT;
    const int NM = in_sizes[1] / DFEAT;
    const int E_um = in_sizes[2];
    const int E_mu = in_sizes[5];

    char* p = (char*)d_ws;
    auto carve = [&](size_t bytes) { char* r = p; p += (bytes + 255) & ~(size_t)255; return r; };
    int* rowptr_m = (int*)carve((size_t)(NM + 1) * 4);
    int* rowptr_u = (int*)carve((size_t)(NU + 1) * 4);
    int* cursor_m = (int*)carve((size_t)NM * 4);
    int* cursor_u = (int*)carve((size_t)NU * 4);
    int* bsum_m   = (int*)carve(64 * 4);
    int* bsum_u   = (int*)carve(64 * 4);
    __bf16* xu_bf = (__bf16*)carve((size_t)NU * DFEAT * 2);
    __bf16* xm_bf = (__bf16*)carve((size_t)NM * DFEAT * 2);
    __bf16* ru_bf = (__bf16*)carve((size_t)NU * DFEAT * 2);
    __bf16* rm_bf = (__bf16*)carve((size_t)NM * DFEAT * 2);
    __bf16* wt_c1um = (__bf16*)carve(256 * 512 * 2);
    __bf16* wt_c1mu = (__bf16*)carve(256 * 512 * 2);
    __bf16* wt_c2um = (__bf16*)carve(256 * 512 * 2);
    __bf16* wt_c2mu = (__bf16*)carve(256 * 512 * 2);

    // int2 records in the dead tail of d_out (consumed before final writes)
    char* dtail = (char*)d_out + (size_t)(NU + NM) * DFEAT * 2;
    int2* rec_m = (int2*)(dtail);
    int2* rec_u = (int2*)(dtail + (size_t)E_um * 8);

    __bf16* mean1_u = (__bf16*)d_out;
    __bf16* mean1_m = (__bf16*)d_out + (size_t)NU * DFEAT;
    float* out_user  = (float*)d_out;
    float* out_movie = (float*)d_out + (size_t)NU * DFEAT;

    // ---- CSR build ----
    size_t msz = ((((size_t)(NM + 1) * 4) + 255) & ~(size_t)255) + (size_t)(NU + 1) * 4;
    hipMemsetAsync(rowptr_m, 0, msz, stream);   // covers rowptr_m + rowptr_u
    hist2_kernel<<<4096, 256, 0, stream>>>(dst_um, E_um, rowptr_m, dst_mu, E_mu, rowptr_u);
    const int nbM = (NM + 1 + 2047) / 2048;
    const int nbU = (NU + 1 + 2047) / 2048;
    scan_block2<<<nbM + nbU, 256, 0, stream>>>(rowptr_m, NM + 1, bsum_m, rowptr_u, NU + 1, bsum_u, nbM);
    scan_sums2<<<1, 128, 0, stream>>>(bsum_m, nbM, bsum_u, nbU);
    scan_add2<<<nbM + nbU, 256, 0, stream>>>(rowptr_m, NM + 1, bsum_m, cursor_m,
                                             rowptr_u, NU + 1, bsum_u, cursor_u, nbM);

    // ---- mega prep: XCD-partitioned fill + bf16 features + packed weights ----
    PrepArgs pa;
    pa.dstA = dst_um; pa.srcA = src_um; pa.wA = w_um; pa.nA = E_um; pa.ndA = NM; pa.curA = cursor_m; pa.recA = rec_m;
    pa.dstB = dst_mu; pa.srcB = src_mu; pa.wB = w_mu; pa.nB = E_mu; pa.ndB = NU; pa.curB = cursor_u; pa.recB = rec_u;
    pa.xu = x_user;  pa.xu_bf = xu_bf; pa.n8u = NU * DFEAT / 8;
    pa.xm = x_movie; pa.xm_bf = xm_bf; pa.n8m = NM * DFEAT / 8;
    pa.Wl[0] = c1_um_Wl; pa.Wr[0] = c1_um_Wr; pa.wout[0] = wt_c1um;
    pa.Wl[1] = c1_mu_Wl; pa.Wr[1] = c1_mu_Wr; pa.wout[1] = wt_c1mu;
    pa.Wl[2] = c2_um_Wl; pa.Wr[2] = c2_um_Wr; pa.wout[2] = wt_c2um;
    pa.Wl[3] = c2_mu_Wl; pa.Wr[3] = c2_mu_Wr; pa.wout[3] = wt_c2mu;
    mega_prep<<<8192, 256, 0, stream>>>(pa);

    const int gaM = (NM + 3) / 4, gaU = (NU + 3) / 4;
    const int gbM = (NM + 63) / 64, gbU = (NU + 63) / 64;

    // ---- layer 1 ----
    agg_dual<<<gaM + gaU, 256, 0, stream>>>(xu_bf, rec_m, rowptr_m, mean1_m, NM, gaM,
                                            xm_bf, rec_u, rowptr_u, mean1_u, NU);
    GemmSide g1m = {mean1_m, xm_bf, wt_c1um, c1_um_b, xm_bf, rm_bf, NM};
    GemmSide g1u = {mean1_u, xu_bf, wt_c1mu, c1_mu_b, xu_bf, ru_bf, NU};
    gemm_dual<1><<<gbM + gbU, 256, 0, stream>>>(g1m, g1u, gbM);

    // ---- layer 2 (means reuse dead x_bf buffers) ----
    __bf16* mean2_m = xm_bf;
    __bf16* mean2_u = xu_bf;
    agg_dual<<<gaM + gaU, 256, 0, stream>>>(ru_bf, rec_m, rowptr_m, mean2_m, NM, gaM,
                                            rm_bf, rec_u, rowptr_u, mean2_u, NU);
    GemmSide g2m = {mean2_m, rm_bf, wt_c2um, c2_um_b, nullptr, out_movie, NM};
    GemmSide g2u = {mean2_u, ru_bf, wt_c2mu, c2_mu_b, nullptr, out_user, NU};
    gemm_dual<0><<<gbM + gbU, 256, 0, stream>>>(g2m, g2u, gbM);
}

// Round 15
// 611.260 us; speedup vs baseline: 1.4659x; 1.0170x over previous
//
#include <hip/hip_runtime.h>
#include <hip/hip_bf16.h>

#define DFEAT 256

typedef __bf16 bf16x8 __attribute__((ext_vector_type(8)));
typedef float  f32x4  __attribute__((ext_vector_type(4)));

// ---------------------------------------------------------------------------
// CSR build: histogram -> hierarchical scan (cursor written in scan_add)
// ---------------------------------------------------------------------------
__global__ void hist2_kernel(const int* __restrict__ dA, int nA, int* __restrict__ PA,
                             const int* __restrict__ dB, int nB, int* __restrict__ PB) {
    int half = gridDim.x >> 1;
    if (blockIdx.x < half) {
        for (int e = blockIdx.x * blockDim.x + threadIdx.x; e < nA; e += half * blockDim.x)
            atomicAdd(&PA[dA[e] + 1], 1);
    } else {
        for (int e = (blockIdx.x - half) * blockDim.x + threadIdx.x; e < nB; e += half * blockDim.x)
            atomicAdd(&PB[dB[e] + 1], 1);
    }
}

__global__ __launch_bounds__(256) void scan_block2(
    int* __restrict__ am, int nm, int* __restrict__ bsm,
    int* __restrict__ au, int nu, int* __restrict__ bsu, int nbM)
{
    __shared__ int wsum[4];
    int* a; int n; int* bsum; int bid;
    if ((int)blockIdx.x < nbM) { a = am; n = nm; bsum = bsm; bid = blockIdx.x; }
    else                       { a = au; n = nu; bsum = bsu; bid = blockIdx.x - nbM; }
    const int tid = threadIdx.x;
    const int lane = tid & 63, wv = tid >> 6;
    const int idx = bid * 2048 + tid * 8;
    int v[8];
    #pragma unroll
    for (int i = 0; i < 8; ++i) v[i] = (idx + i < n) ? a[idx + i] : 0;
    #pragma unroll
    for (int i = 1; i < 8; ++i) v[i] += v[i - 1];
    int tsum = v[7];
    int sc = tsum;
    #pragma unroll
    for (int off = 1; off < 64; off <<= 1) {
        int t = __shfl_up(sc, off);
        if (lane >= off) sc += t;
    }
    if (lane == 63) wsum[wv] = sc;
    __syncthreads();
    int wadd = 0;
    for (int w2 = 0; w2 < wv; ++w2) wadd += wsum[w2];
    int texcl = sc - tsum + wadd;
    #pragma unroll
    for (int i = 0; i < 8; ++i)
        if (idx + i < n) a[idx + i] = v[i] + texcl;
    if (tid == 255) bsum[bid] = sc + wadd;
}

__global__ void scan_sums2(int* __restrict__ bsm, int nbM, int* __restrict__ bsu, int nbU) {
    int wv = threadIdx.x >> 6;
    int lane = threadIdx.x & 63;
    int* bs = wv ? bsu : bsm;
    int nb  = wv ? nbU : nbM;
    int v = (lane < nb) ? bs[lane] : 0;
    #pragma unroll
    for (int off = 1; off < 64; off <<= 1) {
        int t = __shfl_up(v, off);
        if (lane >= off) v += t;
    }
    if (lane < nb) bs[lane] = v;
}

// adds block prefixes AND writes the cursor copy (cursor[d] = rowptr[d])
__global__ __launch_bounds__(256) void scan_add2(
    int* __restrict__ am, int nm, const int* __restrict__ bsm, int* __restrict__ curM,
    int* __restrict__ au, int nu, const int* __restrict__ bsu, int* __restrict__ curU, int nbM)
{
    int* a; int n; const int* bsum; int* cur; int bid;
    if ((int)blockIdx.x < nbM) { a = am; n = nm; bsum = bsm; cur = curM; bid = blockIdx.x; }
    else                       { a = au; n = nu; bsum = bsu; cur = curU; bid = blockIdx.x - nbM; }
    int add = (bid == 0) ? 0 : bsum[bid - 1];
    int idx = bid * 2048 + threadIdx.x * 8;
    #pragma unroll
    for (int i = 0; i < 8; ++i) {
        if (idx + i < n) {
            int v = a[idx + i] + add;
            if (bid > 0) a[idx + i] = v;
            if (idx + i < n - 1) cur[idx + i] = v;
        }
    }
}

// ---------------------------------------------------------------------------
// Mega-prep: [0,4096) XCD-partitioned edge fill (4B packed records) |
// [4096,6144) f32->bf16 | [6144,8192) packed weight transpose.
// Record = (src << 15) | wq, wq = round(w * 32768) in [0,32767]
// (w in [0,1); abs err <= 1.5e-5 -- negligible vs bf16 feature rounding).
// 4B records halve payload AND halve per-XCD active line window (1MB/XCD)
// -> L2 accumulates ~16 stores/line before one writeback.
// ---------------------------------------------------------------------------
struct PrepArgs {
    const int* dstA; const int* srcA; const float* wA; int nA; int ndA;
    int* curA; unsigned int* recA;
    const int* dstB; const int* srcB; const float* wB; int nB; int ndB;
    int* curB; unsigned int* recB;
    const float* xu; __bf16* xu_bf; int n8u;
    const float* xm; __bf16* xm_bf; int n8m;
    const float* Wl[4]; const float* Wr[4]; __bf16* wout[4];
};

__global__ __launch_bounds__(256) void mega_prep(PrepArgs p) {
    const int b = blockIdx.x;
    const int tid = threadIdx.x;
    if (b < 4096) {
        const int* dst; const int* src; const float* w; int n; int ndst; int* cur; unsigned int* rec;
        int within;
        if (b < 2048) { dst = p.dstA; src = p.srcA; w = p.wA; n = p.nA; ndst = p.ndA; cur = p.curA; rec = p.recA; within = b; }
        else          { dst = p.dstB; src = p.srcB; w = p.wB; n = p.nB; ndst = p.ndB; cur = p.curB; rec = p.recB; within = b - 2048; }
        const int r  = within & 7;          // dst-range == XCD group (blockIdx%8)
        const int lb = within >> 3;         // 0..255 within range-group
        const int rsz = (ndst + 7) >> 3;
        const int d0 = r * rsz;
        const int d1 = (d0 + rsz < ndst) ? d0 + rsz : ndst;
        for (int e = lb * 256 + tid; e < n; e += 256 * 256) {
            int d = dst[e];                 // coalesced; L3-hot after pass 1
            if (d >= d0 && d < d1) {
                int pos = atomicAdd(&cur[d], 1);
                unsigned int wq = (unsigned int)fminf(rintf(w[e] * 32768.0f), 32767.0f);
                rec[pos] = ((unsigned int)src[e] << 15) | wq;
            }
        }
    } else if (b < 6144) {
        int total = p.n8u + p.n8m;
        for (int i = (b - 4096) * 256 + tid; i < total; i += 2048 * 256) {
            const float* in; __bf16* out; int j;
            if (i < p.n8u) { in = p.xu; out = p.xu_bf; j = i; }
            else           { in = p.xm; out = p.xm_bf; j = i - p.n8u; }
            float4 x = *reinterpret_cast<const float4*>(in + (size_t)j * 8);
            float4 y = *reinterpret_cast<const float4*>(in + (size_t)j * 8 + 4);
            bf16x8 v;
            v[0] = (__bf16)x.x; v[1] = (__bf16)x.y; v[2] = (__bf16)x.z; v[3] = (__bf16)x.w;
            v[4] = (__bf16)y.x; v[5] = (__bf16)y.y; v[6] = (__bf16)y.z; v[7] = (__bf16)y.w;
            *reinterpret_cast<bf16x8*>(out + (size_t)j * 8) = v;
        }
    } else {
        // packed fragment-major weights: frag f = ncg*16+kc; lane l bytes f*1024+l*16
        int t = (b - 6144) * 256 + tid;          // 0 .. 524287
        int set = t >> 17;
        int e2  = t & 131071;
        int f = e2 >> 9;
        int e = e2 & 511;
        int l = e >> 3;
        int j = e & 7;
        int ncg = f >> 4;
        int kc  = f & 15;
        int col = ncg * 16 + (l & 15);
        int k   = kc * 32 + (l >> 4) * 8 + j;
        float v = (k < 256) ? p.Wl[set][(size_t)k * 256 + col]
                            : p.Wr[set][(size_t)(k - 256) * 256 + col];
        p.wout[set][e2] = (__bf16)v;
    }
}

// ---------------------------------------------------------------------------
// Dual aggregation (movie side blocks [0,nbA), user side rest): one wave per
// dst row; 2 edges per wave-step (32 lanes x 16B), 16 edges in flight;
// cross-half combine via shfl_xor(32). Records are 4B packed (src<<15 | wq).
// ---------------------------------------------------------------------------
__global__ __launch_bounds__(256) void agg_dual(
    const __bf16* __restrict__ xA, const unsigned int* __restrict__ recA,
    const int* __restrict__ rpA, __bf16* __restrict__ meanA, int ndA, int nbA,
    const __bf16* __restrict__ xB, const unsigned int* __restrict__ recB,
    const int* __restrict__ rpB, __bf16* __restrict__ meanB, int ndB)
{
    const __bf16* xsrc; const unsigned int* rec; const int* rowptr; __bf16* mean; int ndst; int lb;
    if ((int)blockIdx.x < nbA) { xsrc = xA; rec = recA; rowptr = rpA; mean = meanA; ndst = ndA; lb = blockIdx.x; }
    else                       { xsrc = xB; rec = recB; rowptr = rpB; mean = meanB; ndst = ndB; lb = blockIdx.x - nbA; }
    int wid  = lb * 4 + (threadIdx.x >> 6);
    int lane = threadIdx.x & 63;
    if (wid >= ndst) return;
    int beg = rowptr[wid], end = rowptr[wid + 1];
    const int half = lane >> 5, hl = lane & 31;
    const __bf16* xcol = xsrc + hl * 8;
    const float wscale = 1.0f / 32768.0f;
    float acc[8];
    #pragma unroll
    for (int i = 0; i < 8; ++i) acc[i] = 0.f;

    int j0 = beg;
    while (j0 < end) {
        int m = end - j0; if (m > 64) m = 64;
        unsigned int rl = (lane < m) ? rec[j0 + lane] : 0u;
        int t = 0;
        for (; t + 16 <= m; t += 16) {
            bf16x8 v[8]; float wt[8];
            #pragma unroll
            for (int u = 0; u < 8; ++u) {
                int tt = t + u * 2;
                unsigned int r0 = (unsigned int)__builtin_amdgcn_readlane((int)rl, tt);
                unsigned int r1 = (unsigned int)__builtin_amdgcn_readlane((int)rl, tt + 1);
                unsigned int rr = half ? r1 : r0;
                wt[u] = (float)(rr & 32767u) * wscale;
                v[u] = *reinterpret_cast<const bf16x8*>(xcol + (size_t)(rr >> 15) * DFEAT);
            }
            #pragma unroll
            for (int u = 0; u < 8; ++u)
                #pragma unroll
                for (int i = 0; i < 8; ++i) acc[i] += wt[u] * (float)v[u][i];
        }
        for (; t < m; t += 2) {
            unsigned int r0 = (unsigned int)__builtin_amdgcn_readlane((int)rl, t);
            unsigned int r1 = (unsigned int)__builtin_amdgcn_readlane((int)rl, (t + 1 < 64) ? t + 1 : 63);
            unsigned int rr = half ? r1 : r0;
            float wv2 = (float)(rr & 32767u) * wscale;
            if (half && t + 1 >= m) wv2 = 0.f;
            bf16x8 v = *reinterpret_cast<const bf16x8*>(xcol + (size_t)(rr >> 15) * DFEAT);
            #pragma unroll
            for (int i = 0; i < 8; ++i) acc[i] += wv2 * (float)v[i];
        }
        j0 += m;
    }

    #pragma unroll
    for (int i = 0; i < 8; ++i) acc[i] += __shfl_xor(acc[i], 32);
    float inv = (end > beg) ? 1.0f / (float)(end - beg) : 0.0f;
    if (half == 0) {
        bf16x8 o;
        #pragma unroll
        for (int i = 0; i < 8; ++i) o[i] = (__bf16)(acc[i] * inv);
        *reinterpret_cast<bf16x8*>(mean + (size_t)wid * DFEAT + hl * 8) = o;
    }
}

// ---------------------------------------------------------------------------
// Dual MFMA GEMM, 2-deep pipeline (R10 structure): out = epi(A@Wl + B@Wr + b)
// ---------------------------------------------------------------------------
struct GemmSide {
    const __bf16* A; const __bf16* B; const __bf16* W;
    const float* bias; const __bf16* resid; void* out; int n;
};

template<int EPI>
__global__ __launch_bounds__(256) void gemm_dual(GemmSide s0, GemmSide s1, int nb0) {
    __shared__ char sA[3][64 * 128];      // 3 x 8 KB

    const GemmSide& S = ((int)blockIdx.x < nb0) ? s0 : s1;
    const int lblk = ((int)blockIdx.x < nb0) ? blockIdx.x : blockIdx.x - nb0;
    const __bf16* __restrict__ Amat = S.A;
    const __bf16* __restrict__ Bmat = S.B;
    const char* Wb = reinterpret_cast<const char*>(S.W);
    const int n = S.n;

    const int tid  = threadIdx.x;
    const int lane = tid & 63;
    const int wv   = tid >> 6;
    const int lo   = lane & 15;
    const int hi   = lane >> 4;
    const int brow = lblk * 64;
    const int wcol = wv * 64;
    const int nm1  = n - 1;

    f32x4 acc[4][4];
    #pragma unroll
    for (int i = 0; i < 4; ++i)
        #pragma unroll
        for (int j = 0; j < 4; ++j) acc[i][j] = (f32x4){0.f, 0.f, 0.f, 0.f};

    auto stage = [&](int chunk, int buf) {
        const __bf16* mat = (chunk < 4) ? Amat : Bmat;
        const int kbyte = (chunk & 3) * 128;
        #pragma unroll
        for (int q = 0; q < 2; ++q) {
            int s = q * 256 + tid;
            int r = s >> 3, sub = s & 7;
            int grow = brow + r; if (grow > nm1) grow = nm1;
            int srcoff = (sub * 16) ^ ((r & 7) << 4);
            const char* g = reinterpret_cast<const char*>(mat) + (size_t)grow * 512 + kbyte + srcoff;
            __builtin_amdgcn_global_load_lds(
                (const __attribute__((address_space(1))) void*)g,
                (__attribute__((address_space(3))) void*)(sA[buf] + s * 16), 16, 0, 0);
        }
    };

    const int lb = lane * 16;
    bf16x8 bqA[2][4], bqB[2][4];
    auto loadB = [&](int chunk, bf16x8 (&dst)[2][4]) {
        #pragma unroll
        for (int ks = 0; ks < 2; ++ks)
            #pragma unroll
            for (int nn = 0; nn < 4; ++nn)
                dst[ks][nn] = *reinterpret_cast<const bf16x8*>(
                    Wb + (size_t)(((wv * 4 + nn) * 16 + chunk * 2 + ks) << 10) + lb);
    };

    stage(0, 0);
    stage(1, 1);
    loadB(0, bqA);

    #pragma unroll
    for (int c = 0; c < 8; ++c) {
        asm volatile("s_waitcnt vmcnt(10)" ::: "memory");
        __builtin_amdgcn_s_barrier();
        __builtin_amdgcn_sched_barrier(0);
        if (c < 6) stage(c + 2, (c + 2) % 3);
        const int cur = c % 3;
        auto compute = [&](bf16x8 (&bq)[2][4]) {
            #pragma unroll
            for (int ks = 0; ks < 2; ++ks) {
                const int kb = ks * 64 + hi * 16;
                #pragma unroll
                for (int mm = 0; mm < 4; ++mm) {
                    int r = mm * 16 + lo;
                    bf16x8 a = *reinterpret_cast<const bf16x8*>(
                        sA[cur] + r * 128 + (kb ^ ((r & 7) << 4)));
                    #pragma unroll
                    for (int nn = 0; nn < 4; ++nn)
                        acc[mm][nn] = __builtin_amdgcn_mfma_f32_16x16x32_bf16(
                            a, bq[ks][nn], acc[mm][nn], 0, 0, 0);
                }
            }
        };
        if ((c & 1) == 0) { if (c < 7) loadB(c + 1, bqB); compute(bqA); }
        else              { if (c < 7) loadB(c + 1, bqA); compute(bqB); }
    }

    #pragma unroll
    for (int mm = 0; mm < 4; ++mm) {
        #pragma unroll
        for (int nn = 0; nn < 4; ++nn) {
            int col = wcol + nn * 16 + lo;
            float bv2 = S.bias[col];
            #pragma unroll
            for (int r = 0; r < 4; ++r) {
                int grow = brow + mm * 16 + hi * 4 + r;
                if (grow >= n) continue;
                float v = acc[mm][nn][r] + bv2;
                if (EPI == 1) {
                    float rv = (float)S.resid[(size_t)grow * DFEAT + col];
                    ((__bf16*)S.out)[(size_t)grow * DFEAT + col] =
                        (__bf16)(rv + fmaxf(v, 0.f));
                } else {
                    ((float*)S.out)[(size_t)grow * DFEAT + col] = v;
                }
            }
        }
    }
}

// ---------------------------------------------------------------------------
extern "C" void kernel_launch(void* const* d_in, const int* in_sizes, int n_in,
                              void* d_out, int out_size, void* d_ws, size_t ws_size,
                              hipStream_t stream) {
    const float* x_user  = (const float*)d_in[0];
    const float* x_movie = (const float*)d_in[1];
    const int*   src_um  = (const int*)d_in[2];
    const int*   dst_um  = (const int*)d_in[3];
    const float* w_um    = (const float*)d_in[4];
    const int*   src_mu  = (const int*)d_in[5];
    const int*   dst_mu  = (const int*)d_in[6];
    const float* w_mu    = (const float*)d_in[7];
    const float* c1_um_Wl = (const float*)d_in[8];
    const float* c1_um_Wr = (const float*)d_in[9];
    const float* c1_um_b  = (const float*)d_in[10];
    const float* c1_mu_Wl = (const float*)d_in[11];
    const float* c1_mu_Wr = (const float*)d_in[12];
    const float* c1_mu_b  = (const float*)d_in[13];
    const float* c2_um_Wl = (const float*)d_in[14];
    const float* c2_um_Wr = (const float*)d_in[15];
    const float* c2_um_b  = (const float*)d_in[16];
    const float* c2_mu_Wl = (const float*)d_in[17];
    const float* c2_mu_Wr = (const float*)d_in[18];
    const float* c2_mu_b  = (const float*)d_in[19];

    const int NU = in_sizes[0] / DFEAT;
    const int NM = in_sizes[1] / DFEAT;
    const int E_um = in_sizes[2];
    const int E_mu = in_sizes[5];

    char* p = (char*)d_ws;
    auto carve = [&](size_t bytes) { char* r = p; p += (bytes + 255) & ~(size_t)255; return r; };
    int* rowptr_m = (int*)carve((size_t)(NM + 1) * 4);
    int* rowptr_u = (int*)carve((size_t)(NU + 1) * 4);
    int* cursor_m = (int*)carve((size_t)NM * 4);
    int* cursor_u = (int*)carve((size_t)NU * 4);
    int* bsum_m   = (int*)carve(64 * 4);
    int* bsum_u   = (int*)carve(64 * 4);
    __bf16* xu_bf = (__bf16*)carve((size_t)NU * DFEAT * 2);
    __bf16* xm_bf = (__bf16*)carve((size_t)NM * DFEAT * 2);
    __bf16* ru_bf = (__bf16*)carve((size_t)NU * DFEAT * 2);
    __bf16* rm_bf = (__bf16*)carve((size_t)NM * DFEAT * 2);
    __bf16* wt_c1um = (__bf16*)carve(256 * 512 * 2);
    __bf16* wt_c1mu = (__bf16*)carve(256 * 512 * 2);
    __bf16* wt_c2um = (__bf16*)carve(256 * 512 * 2);
    __bf16* wt_c2mu = (__bf16*)carve(256 * 512 * 2);

    // 4B packed records in the dead tail of d_out (consumed before final writes)
    char* dtail = (char*)d_out + (size_t)(NU + NM) * DFEAT * 2;
    unsigned int* rec_m = (unsigned int*)(dtail);
    unsigned int* rec_u = (unsigned int*)(dtail + (size_t)E_um * 4);

    __bf16* mean1_u = (__bf16*)d_out;
    __bf16* mean1_m = (__bf16*)d_out + (size_t)NU * DFEAT;
    float* out_user  = (float*)d_out;
    float* out_movie = (float*)d_out + (size_t)NU * DFEAT;

    // ---- CSR build ----
    size_t msz = ((((size_t)(NM + 1) * 4) + 255) & ~(size_t)255) + (size_t)(NU + 1) * 4;
    hipMemsetAsync(rowptr_m, 0, msz, stream);   // covers rowptr_m + rowptr_u
    hist2_kernel<<<4096, 256, 0, stream>>>(dst_um, E_um, rowptr_m, dst_mu, E_mu, rowptr_u);
    const int nbM = (NM + 1 + 2047) / 2048;
    const int nbU = (NU + 1 + 2047) / 2048;
    scan_block2<<<nbM + nbU, 256, 0, stream>>>(rowptr_m, NM + 1, bsum_m, rowptr_u, NU + 1, bsum_u, nbM);
    scan_sums2<<<1, 128, 0, stream>>>(bsum_m, nbM, bsum_u, nbU);
    scan_add2<<<nbM + nbU, 256, 0, stream>>>(rowptr_m, NM + 1, bsum_m, cursor_m,
                                             rowptr_u, NU + 1, bsum_u, cursor_u, nbM);

    // ---- mega prep: XCD-partitioned fill + bf16 features + packed weights ----
    PrepArgs pa;
    pa.dstA = dst_um; pa.srcA = src_um; pa.wA = w_um; pa.nA = E_um; pa.ndA = NM; pa.curA = cursor_m; pa.recA = rec_m;
    pa.dstB = dst_mu; pa.srcB = src_mu; pa.wB = w_mu; pa.nB = E_mu; pa.ndB = NU; pa.curB = cursor_u; pa.recB = rec_u;
    pa.xu = x_user;  pa.xu_bf = xu_bf; pa.n8u = NU * DFEAT / 8;
    pa.xm = x_movie; pa.xm_bf = xm_bf; pa.n8m = NM * DFEAT / 8;
    pa.Wl[0] = c1_um_Wl; pa.Wr[0] = c1_um_Wr; pa.wout[0] = wt_c1um;
    pa.Wl[1] = c1_mu_Wl; pa.Wr[1] = c1_mu_Wr; pa.wout[1] = wt_c1mu;
    pa.Wl[2] = c2_um_Wl; pa.Wr[2] = c2_um_Wr; pa.wout[2] = wt_c2um;
    pa.Wl[3] = c2_mu_Wl; pa.Wr[3] = c2_mu_Wr; pa.wout[3] = wt_c2mu;
    mega_prep<<<8192, 256, 0, stream>>>(pa);

    const int gaM = (NM + 3) / 4, gaU = (NU + 3) / 4;
    const int gbM = (NM + 63) / 64, gbU = (NU + 63) / 64;

    // ---- layer 1 ----
    agg_dual<<<gaM + gaU, 256, 0, stream>>>(xu_bf, rec_m, rowptr_m, mean1_m, NM, gaM,
                                            xm_bf, rec_u, rowptr_u, mean1_u, NU);
    GemmSide g1m = {mean1_m, xm_bf, wt_c1um, c1_um_b, xm_bf, rm_bf, NM};
    GemmSide g1u = {mean1_u, xu_bf, wt_c1mu, c1_mu_b, xu_bf, ru_bf, NU};
    gemm_dual<1><<<gbM + gbU, 256, 0, stream>>>(g1m, g1u, gbM);

    // ---- layer 2 (means reuse dead x_bf buffers) ----
    __bf16* mean2_m = xm_bf;
    __bf16* mean2_u = xu_bf;
    agg_dual<<<gaM + gaU, 256, 0, stream>>>(ru_bf, rec_m, rowptr_m, mean2_m, NM, gaM,
                                            rm_bf, rec_u, rowptr_u, mean2_u, NU);
    GemmSide g2m = {mean2_m, rm_bf, wt_c2um, c2_um_b, nullptr, out_movie, NM};
    GemmSide g2u = {mean2_u, ru_bf, wt_c2mu, c2_mu_b, nullptr, out_user, NU};
    gemm_dual<0><<<gbM + gbU, 256, 0, stream>>>(g2m, g2u, gbM);
}